// Round 6
// baseline (1391.083 us; speedup 1.0000x reference)
//
#include <hip/hip_runtime.h>

#define HD 14
#define NOUT 2
#define NN 200000
#define EE 3200000
#define GG 2000

// bucket config
#define WNODE 256                         // nodes per bucket (c >> 8)
#define NBIN 782                          // ceil(200000/256)
#define NBLKA 256                         // partition blocks
#define EPERA 12500                       // edges per partition block
#define NCELL (NBIN*NBLKA)                // 200192
#define TILE 2048                         // edges per in-block sort tile

// scan config
#define SBS 256
#define SEL 8
#define CHUNK (SBS*SEL)                   // 2048
#define NBSCAN ((NCELL + CHUNK - 1) / CHUNK)  // 98

__device__ __forceinline__ float psi_f(float v) {
    float r = log1pf(fabsf(v));
    return v < 0.f ? -r : r;
}

__device__ __forceinline__ void stage_f(float* dst, const float* src, int n) {
    for (int i = threadIdx.x; i < n; i += blockDim.x) dst[i] = src[i];
}

__device__ __forceinline__ int lower_bound_i(const int* a, int n, int key) {
    int lo = 0, hi = n;
    while (lo < hi) { int mid = (lo + hi) >> 1; if (a[mid] < key) lo = mid + 1; else hi = mid; }
    return lo;
}

// ---- pass 0: fold We2 into Wn11 ----
// C[k][j] = sum_t We2[k][t]*Wn11[1+t][j];  bp[j] = bn11[j] + sum_t be2[t]*Wn11[1+t][j]
__global__ void __launch_bounds__(256)
fold_kernel(const float* __restrict__ We2, const float* __restrict__ be2,
            const float* __restrict__ Wn11, const float* __restrict__ bn11,
            float* __restrict__ C, float* __restrict__ bp)
{
    int t = threadIdx.x;
    if (t < HD*HD) {
        int k = t / HD, j = t % HD;
        float s = 0.f;
        #pragma unroll
        for (int u = 0; u < HD; ++u) s = fmaf(We2[k*HD+u], Wn11[(1+u)*HD+j], s);
        C[t] = s;
    } else if (t < HD*HD + HD) {
        int j = t - HD*HD;
        float s = bn11[j];
        #pragma unroll
        for (int u = 0; u < HD; ++u) s = fmaf(be2[u], Wn11[(1+u)*HD+j], s);
        bp[j] = s;
    }
}

// ---- pass 1: per-(bucket, block) histogram of col>>8, bin-major output ----
__global__ void __launch_bounds__(256)
histA(const int* __restrict__ col, int* __restrict__ ghist)
{
    __shared__ int hist[NBIN];
    int tid = threadIdx.x;
    for (int i = tid; i < NBIN; i += 256) hist[i] = 0;
    __syncthreads();
    int j = blockIdx.x;
    int base = j * EPERA;
    for (int it = 0; it < EPERA; it += 256) {
        int o = it + tid;
        if (o < EPERA) atomicAdd(&hist[col[base + o] >> 8], 1);
    }
    __syncthreads();
    for (int i = tid; i < NBIN; i += 256) ghist[i * NBLKA + j] = hist[i];
}

// ---- scan of ghist[NCELL] -> excl (chunk-local) + btot (chunk bases) ----
__global__ void __launch_bounds__(SBS)
scan1_kernel(const int* __restrict__ cnt, int* __restrict__ excl,
             int* __restrict__ btot, int n)
{
    __shared__ int lds[SBS];
    int tid = threadIdx.x;
    int base = blockIdx.x * CHUNK + tid * SEL;
    int v[SEL]; int s = 0;
    #pragma unroll
    for (int k = 0; k < SEL; ++k) { int i = base + k; v[k] = (i < n) ? cnt[i] : 0; s += v[k]; }
    lds[tid] = s; __syncthreads();
    for (int off = 1; off < SBS; off <<= 1) {
        int t = (tid >= off) ? lds[tid - off] : 0;
        __syncthreads();
        lds[tid] += t;
        __syncthreads();
    }
    int incl = lds[tid];
    int run = incl - s;
    if (tid == SBS - 1) btot[blockIdx.x] = incl;
    #pragma unroll
    for (int k = 0; k < SEL; ++k) { int i = base + k; if (i < n) excl[i] = run; run += v[k]; }
}

__global__ void __launch_bounds__(256)
scan2_kernel(int* __restrict__ btot, int nb)
{
    __shared__ int lds[256];
    int tid = threadIdx.x;
    int v = (tid < nb) ? btot[tid] : 0;
    lds[tid] = v; __syncthreads();
    for (int off = 1; off < 256; off <<= 1) {
        int t = (tid >= off) ? lds[tid - off] : 0;
        __syncthreads();
        lds[tid] += t;
        __syncthreads();
    }
    if (tid < nb) btot[tid] = lds[tid] - v;   // exclusive chunk bases, in place
}

// ---- pass 2: partition edges into buckets, packed (src | dl<<18) ----
__global__ void __launch_bounds__(256)
scatterA(const int* __restrict__ row, const int* __restrict__ col,
         const int* __restrict__ excl, const int* __restrict__ btot,
         int* __restrict__ srcdst)
{
    __shared__ int lcount[NBIN];
    int tid = threadIdx.x;
    for (int i = tid; i < NBIN; i += 256) lcount[i] = 0;
    __syncthreads();
    int j = blockIdx.x;
    int base = j * EPERA;
    for (int it = 0; it < EPERA; it += 256) {
        int o = it + tid;
        if (o < EPERA) {
            int e = base + o;
            int c = col[e];
            int r = row[e];
            int bb = c >> 8;
            int dl = c & 255;
            int rk = atomicAdd(&lcount[bb], 1);
            int cell = bb * NBLKA + j;
            int pos = excl[cell] + btot[cell >> 11] + rk;
            srcdst[pos] = r | (dl << 18);
        }
    }
}

// ---- pass 3: per-bucket tile counting-sort + node-serial fused compute ----
__global__ void __launch_bounds__(256, 4)
bucket_kernel(const float4* __restrict__ x,
              const int* __restrict__ srcdst,
              const int* __restrict__ excl, const int* __restrict__ btot,
              const float* __restrict__ We1, const float* __restrict__ be1,
              const float* __restrict__ Wn11,    // row 0 used
              const float* __restrict__ C, const float* __restrict__ bp,
              const float* __restrict__ Wn12, const float* __restrict__ bn12,
              const float* __restrict__ Wn21, const float* __restrict__ bn21,
              const float* __restrict__ Wn22, const float* __restrict__ bn22,
              float* __restrict__ x_out, int N, int E)
{
    // transposed/padded inner-loop weights for contiguous LDS reads
    __shared__ float sWe1t[HD*4];       // [j][i]  h1-layer
    __shared__ float sCt[HD*16];        // [j][k] padded to 16
    __shared__ float sbe1[HD], sW11[HD], sbp[HD];
    __shared__ float sW12[HD*HD], sb12[HD];
    __shared__ float sW21[(1+HD)*HD], sb21[HD], sW22[HD*HD], sb22[HD];
    __shared__ float4 xn[WNODE];
    __shared__ float nf2[WNODE];
    __shared__ int hist[WNODE];
    __shared__ int offs[WNODE];
    __shared__ int sorted[TILE];

    int tid = threadIdx.x;

    // stage weights (transposed where hot)
    if (tid < HD*4) {                       // sWe1t[j*4+i] = We1[i*HD+j]
        int j = tid >> 2, i = tid & 3;
        sWe1t[tid] = We1[i*HD + j];
    }
    {   // sCt[j*16+k] = C[k*HD+j] (k<HD else 0)
        for (int t = tid; t < HD*16; t += 256) {
            int j = t >> 4, k = t & 15;
            sCt[t] = (k < HD) ? C[k*HD + j] : 0.f;
        }
    }
    stage_f(sbe1, be1, HD);  stage_f(sW11, Wn11, HD);  stage_f(sbp, bp, HD);
    stage_f(sW12, Wn12, HD*HD); stage_f(sb12, bn12, HD);
    stage_f(sW21, Wn21, (1+HD)*HD); stage_f(sb21, bn21, HD);
    stage_f(sW22, Wn22, HD*HD); stage_f(sb22, bn22, HD);

    int b = blockIdx.x;
    int nb0 = b * WNODE;
    int nN = min(WNODE, N - nb0);

    if (tid < nN) {
        float4 v = x[nb0 + tid];
        xn[tid] = v;
        float ip = -v.x*v.x + v.y*v.y + v.z*v.z + v.w*v.w;
        nf2[tid] = psi_f(ip);
    }

    int c0 = b * NBLKA;
    int lo = excl[c0] + btot[c0 >> 11];
    int hi;
    if (b + 1 < NBIN) { int c1 = (b + 1) * NBLKA; hi = excl[c1] + btot[c1 >> 11]; }
    else hi = E;

    float acc[HD];
    #pragma unroll
    for (int j = 0; j < HD; ++j) acc[j] = 0.f;
    int deg = 0;

    __syncthreads();

    for (int tb = lo; tb < hi; tb += TILE) {
        int tsz = min(TILE, hi - tb);

        hist[tid] = 0;
        __syncthreads();

        int pk[8]; int rk[8];
        #pragma unroll
        for (int k = 0; k < 8; ++k) {
            int o = k * 256 + tid;
            if (o < tsz) {
                int p = srcdst[tb + o];
                pk[k] = p;
                rk[k] = atomicAdd(&hist[(p >> 18) & 255], 1);
            } else { pk[k] = -1; rk[k] = 0; }
        }
        __syncthreads();

        // inclusive scan hist -> offs
        offs[tid] = hist[tid];
        __syncthreads();
        for (int st = 1; st < 256; st <<= 1) {
            int v = (tid >= st) ? offs[tid - st] : 0;
            __syncthreads();
            offs[tid] += v;
            __syncthreads();
        }

        // scatter to sorted LDS (exclusive base = offs[dl] - hist[dl])
        #pragma unroll
        for (int k = 0; k < 8; ++k) {
            if (pk[k] >= 0) {
                int dl = (pk[k] >> 18) & 255;
                sorted[offs[dl] - hist[dl] + rk[k]] = pk[k];
            }
        }
        __syncthreads();

        // phase 2: thread tid == node tid, serial over its contiguous run
        int cntt = hist[tid];
        if (cntt > 0) {
            int start = offs[tid] - cntt;
            float4 bx = xn[tid];
            float f2 = nf2[tid];

            int p = sorted[start];
            float4 a = x[p & 262143];
            for (int i = 0; i < cntt; ++i) {
                float4 an; int pn = 0;
                if (i + 1 < cntt) { pn = sorted[start + i + 1]; an = x[pn & 262143]; }

                float f0 = -a.x*a.x + a.y*a.y + a.z*a.z + a.w*a.w;
                float f1 = -a.x*bx.x + a.y*bx.y + a.z*bx.z + a.w*bx.w;
                float dx = a.x-bx.x, dy = a.y-bx.y, dz = a.z-bx.z, dw = a.w-bx.w;
                float f3 = psi_f(-dx*dx + dy*dy + dz*dz + dw*dw);

                float h1[HD];
                #pragma unroll
                for (int j = 0; j < HD; ++j) {
                    float v = f0*sWe1t[j*4+0] + f1*sWe1t[j*4+1] + f2*sWe1t[j*4+2] + f3*sWe1t[j*4+3] + sbe1[j];
                    h1[j] = fmaxf(v, 0.f);
                }
                #pragma unroll
                for (int j = 0; j < HD; ++j) {
                    float v = fmaf(f0, sW11[j], sbp[j]);
                    #pragma unroll
                    for (int k2 = 0; k2 < HD; ++k2) v = fmaf(h1[k2], sCt[j*16+k2], v);
                    acc[j] += fmaxf(v, 0.f);
                }
                a = an;
            }
            deg += cntt;
        }
        __syncthreads();
    }

    // finalize node tid
    if (tid < nN) {
        float aggm[HD];
        if (deg > 0) {
            float inv = 1.0f / (float)deg;
            float am[HD];
            #pragma unroll
            for (int k = 0; k < HD; ++k) am[k] = acc[k] * inv;
            #pragma unroll
            for (int j = 0; j < HD; ++j) {
                float v = sb12[j];
                #pragma unroll
                for (int k = 0; k < HD; ++k) v = fmaf(am[k], sW12[k*HD+j], v);
                aggm[j] = v;
            }
        } else {
            #pragma unroll
            for (int j = 0; j < HD; ++j) aggm[j] = 0.f;
        }

        float4 v4 = xn[tid];
        float ipbb = -v4.x*v4.x + v4.y*v4.y + v4.z*v4.z + v4.w*v4.w;
        float h[HD];
        #pragma unroll
        for (int j = 0; j < HD; ++j) {
            float v = fmaf(ipbb, sW21[j], sb21[j]);
            #pragma unroll
            for (int k = 0; k < HD; ++k) v = fmaf(aggm[k], sW21[(1+k)*HD+j], v);
            h[j] = fmaxf(v, 0.f);
        }
        float xo[16];
        #pragma unroll
        for (int j = 0; j < HD; ++j) {
            float v = sb22[j];
            #pragma unroll
            for (int k = 0; k < HD; ++k) v = fmaf(h[k], sW22[k*HD+j], v);
            xo[j] = v;
        }
        float4* op = (float4*)(x_out + (size_t)(nb0 + tid) * 16);
        op[0] = make_float4(xo[0], xo[1], xo[2], xo[3]);
        op[1] = make_float4(xo[4], xo[5], xo[6], xo[7]);
        op[2] = make_float4(xo[8], xo[9], xo[10], xo[11]);
        op[3] = make_float4(xo[12], xo[13], 0.f, 0.f);
    }
}

// ---- pass 4: per-graph mean (batch sorted -> contiguous ranges) + global MLP ----
__global__ void __launch_bounds__(256)
graph_kernel(const float* __restrict__ x_out, const int* __restrict__ batch,
             const float* __restrict__ Wg1, const float* __restrict__ bg1,
             const float* __restrict__ Wg2, const float* __restrict__ bg2,
             float* __restrict__ out, int N, int G)
{
    __shared__ float red[256 * 15];
    int g = blockIdx.x;
    int tid = threadIdx.x;

    int lo = lower_bound_i(batch, N, g);
    int hi = lower_bound_i(batch, N, g + 1);

    float acc[HD];
    #pragma unroll
    for (int j = 0; j < HD; ++j) acc[j] = 0.f;

    for (int n = lo + tid; n < hi; n += 256) {
        const float* xp = x_out + (size_t)n * 16;
        #pragma unroll
        for (int j = 0; j < HD; ++j) acc[j] += xp[j];
    }
    #pragma unroll
    for (int j = 0; j < HD; ++j) red[tid * 15 + j] = acc[j];
    __syncthreads();

    for (int s = 128; s >= 1; s >>= 1) {
        if (tid < s) {
            #pragma unroll
            for (int j = 0; j < HD; ++j) red[tid * 15 + j] += red[(tid + s) * 15 + j];
        }
        __syncthreads();
    }

    if (tid == 0) {
        float invc = 1.0f / fmaxf((float)(hi - lo), 1.0f);
        float gm[HD];
        #pragma unroll
        for (int j = 0; j < HD; ++j) gm[j] = red[j] * invc;
        float h[HD];
        #pragma unroll
        for (int j = 0; j < HD; ++j) {
            float v = bg1[j];
            #pragma unroll
            for (int k = 0; k < HD; ++k) v = fmaf(gm[k], Wg1[k*HD+j], v);
            h[j] = fmaxf(v, 0.f);
        }
        #pragma unroll
        for (int o = 0; o < NOUT; ++o) {
            float v = bg2[o];
            #pragma unroll
            for (int k = 0; k < HD; ++k) v = fmaf(h[k], Wg2[k*NOUT+o], v);
            out[g * NOUT + o] = v;
        }
    }
}

extern "C" void kernel_launch(void* const* d_in, const int* in_sizes, int n_in,
                              void* d_out, int out_size, void* d_ws, size_t ws_size,
                              hipStream_t stream) {
    const int N = NN, E = EE, G = GG;

    const float4* x     = (const float4*)d_in[0];
    const int*    eidx  = (const int*)d_in[1];
    const int*    batch = (const int*)d_in[2];
    const float*  We1  = (const float*)d_in[3];
    const float*  be1  = (const float*)d_in[4];
    const float*  We2  = (const float*)d_in[5];
    const float*  be2  = (const float*)d_in[6];
    const float*  Wn11 = (const float*)d_in[7];
    const float*  bn11 = (const float*)d_in[8];
    const float*  Wn12 = (const float*)d_in[9];
    const float*  bn12 = (const float*)d_in[10];
    const float*  Wn21 = (const float*)d_in[11];
    const float*  bn21 = (const float*)d_in[12];
    const float*  Wn22 = (const float*)d_in[13];
    const float*  bn22 = (const float*)d_in[14];
    const float*  Wg1  = (const float*)d_in[15];
    const float*  bg1  = (const float*)d_in[16];
    const float*  Wg2  = (const float*)d_in[17];
    const float*  bg2  = (const float*)d_in[18];

    const int* row = eidx;       // edge_index[0]
    const int* col = eidx + E;   // edge_index[1]

    // workspace layout (bytes) — every buffer fully written before read, no memsets:
    //   ghist  @ 0          NCELL ints  (800,768)
    //   excl   @ 1,048,576  NCELL ints  (800,768)
    //   btot   @ 1,900,544  NBSCAN ints (392)
    //   Cfold  @ 1,901,568  (784)
    //   bfold  @ 1,902,592  (56)
    //   srcdst @ 2,097,152  E ints      (12,800,000) -> ends 14,897,152
    //   x_out  @ 14,897,152 N*16 floats (12,800,000) -> ends 27,697,152
    char*  ws     = (char*)d_ws;
    int*   ghist  = (int*)(ws + 0);
    int*   excl   = (int*)(ws + 1048576);
    int*   btot   = (int*)(ws + 1900544);
    float* Cfold  = (float*)(ws + 1901568);
    float* bfold  = (float*)(ws + 1902592);
    int*   srcdst = (int*)(ws + 2097152);
    float* x_out  = (float*)(ws + 14897152);

    dim3 blk(256);
    fold_kernel<<<dim3(1), blk, 0, stream>>>(We2, be2, Wn11, bn11, Cfold, bfold);

    histA<<<dim3(NBLKA), blk, 0, stream>>>(col, ghist);
    scan1_kernel<<<dim3(NBSCAN), dim3(SBS), 0, stream>>>(ghist, excl, btot, NCELL);
    scan2_kernel<<<dim3(1), blk, 0, stream>>>(btot, NBSCAN);
    scatterA<<<dim3(NBLKA), blk, 0, stream>>>(row, col, excl, btot, srcdst);

    bucket_kernel<<<dim3(NBIN), blk, 0, stream>>>(
        x, srcdst, excl, btot,
        We1, be1, Wn11, Cfold, bfold,
        Wn12, bn12, Wn21, bn21, Wn22, bn22,
        x_out, N, E);

    graph_kernel<<<dim3(G), blk, 0, stream>>>(x_out, batch, Wg1, bg1, Wg2, bg2,
                                              (float*)d_out, N, G);
}

// Round 7
// 282.040 us; speedup vs baseline: 4.9322x; 4.9322x over previous
//
#include <hip/hip_runtime.h>

#define HD 14
#define NOUT 2
#define NN 200000
#define EE 3200000
#define GG 2000

// bucket config
#define WNODE 256                         // nodes per bucket (c >> 8)
#define NBIN 782                          // ceil(200000/256)
#define NBLKA 256                         // partition blocks
#define EPERA 12500                       // edges per partition block
#define NCELL (NBIN*NBLKA)                // 200192
#define TILE 4096                         // edges per in-block sort tile

// scan config
#define SBS 256
#define SEL 8
#define CHUNK (SBS*SEL)                   // 2048
#define NBSCAN ((NCELL + CHUNK - 1) / CHUNK)  // 98

__device__ __forceinline__ float psi_f(float v) {
    float r = log1pf(fabsf(v));
    return v < 0.f ? -r : r;
}

__device__ __forceinline__ void stage_f(float* dst, const float* src, int n) {
    for (int i = threadIdx.x; i < n; i += blockDim.x) dst[i] = src[i];
}

__device__ __forceinline__ int lower_bound_i(const int* a, int n, int key) {
    int lo = 0, hi = n;
    while (lo < hi) { int mid = (lo + hi) >> 1; if (a[mid] < key) lo = mid + 1; else hi = mid; }
    return lo;
}

// ---- pass 0: fold We2 into Wn11 ----
__global__ void __launch_bounds__(256)
fold_kernel(const float* __restrict__ We2, const float* __restrict__ be2,
            const float* __restrict__ Wn11, const float* __restrict__ bn11,
            float* __restrict__ C, float* __restrict__ bp)
{
    int t = threadIdx.x;
    if (t < HD*HD) {
        int k = t / HD, j = t % HD;
        float s = 0.f;
        #pragma unroll
        for (int u = 0; u < HD; ++u) s = fmaf(We2[k*HD+u], Wn11[(1+u)*HD+j], s);
        C[t] = s;
    } else if (t < HD*HD + HD) {
        int j = t - HD*HD;
        float s = bn11[j];
        #pragma unroll
        for (int u = 0; u < HD; ++u) s = fmaf(be2[u], Wn11[(1+u)*HD+j], s);
        bp[j] = s;
    }
}

// ---- pass 1: per-(bucket, block) histogram of col>>8, bin-major output ----
__global__ void __launch_bounds__(256)
histA(const int* __restrict__ col, int* __restrict__ ghist)
{
    __shared__ int hist[NBIN];
    int tid = threadIdx.x;
    for (int i = tid; i < NBIN; i += 256) hist[i] = 0;
    __syncthreads();
    int j = blockIdx.x;
    int base = j * EPERA;
    for (int it = 0; it < EPERA; it += 256) {
        int o = it + tid;
        if (o < EPERA) atomicAdd(&hist[col[base + o] >> 8], 1);
    }
    __syncthreads();
    for (int i = tid; i < NBIN; i += 256) ghist[i * NBLKA + j] = hist[i];
}

// ---- scan of ghist[NCELL] -> excl (chunk-local) + btot (chunk bases) ----
__global__ void __launch_bounds__(SBS)
scan1_kernel(const int* __restrict__ cnt, int* __restrict__ excl,
             int* __restrict__ btot, int n)
{
    __shared__ int lds[SBS];
    int tid = threadIdx.x;
    int base = blockIdx.x * CHUNK + tid * SEL;
    int v[SEL]; int s = 0;
    #pragma unroll
    for (int k = 0; k < SEL; ++k) { int i = base + k; v[k] = (i < n) ? cnt[i] : 0; s += v[k]; }
    lds[tid] = s; __syncthreads();
    for (int off = 1; off < SBS; off <<= 1) {
        int t = (tid >= off) ? lds[tid - off] : 0;
        __syncthreads();
        lds[tid] += t;
        __syncthreads();
    }
    int incl = lds[tid];
    int run = incl - s;
    if (tid == SBS - 1) btot[blockIdx.x] = incl;
    #pragma unroll
    for (int k = 0; k < SEL; ++k) { int i = base + k; if (i < n) excl[i] = run; run += v[k]; }
}

__global__ void __launch_bounds__(256)
scan2_kernel(int* __restrict__ btot, int nb)
{
    __shared__ int lds[256];
    int tid = threadIdx.x;
    int v = (tid < nb) ? btot[tid] : 0;
    lds[tid] = v; __syncthreads();
    for (int off = 1; off < 256; off <<= 1) {
        int t = (tid >= off) ? lds[tid - off] : 0;
        __syncthreads();
        lds[tid] += t;
        __syncthreads();
    }
    if (tid < nb) btot[tid] = lds[tid] - v;   // exclusive chunk bases, in place
}

// ---- pass 2: partition edges into buckets, packed (src | dl<<18) ----
__global__ void __launch_bounds__(256)
scatterA(const int* __restrict__ row, const int* __restrict__ col,
         const int* __restrict__ excl, const int* __restrict__ btot,
         int* __restrict__ srcdst)
{
    __shared__ int lcount[NBIN];
    int tid = threadIdx.x;
    for (int i = tid; i < NBIN; i += 256) lcount[i] = 0;
    __syncthreads();
    int j = blockIdx.x;
    int base = j * EPERA;
    for (int it = 0; it < EPERA; it += 256) {
        int o = it + tid;
        if (o < EPERA) {
            int e = base + o;
            int c = col[e];
            int r = row[e];
            int bb = c >> 8;
            int dl = c & 255;
            int rk = atomicAdd(&lcount[bb], 1);
            int cell = bb * NBLKA + j;
            int pos = excl[cell] + btot[cell >> 11] + rk;
            srcdst[pos] = r | (dl << 18);
        }
    }
}

// ---- pass 3: per-bucket tile counting-sort + node-serial fused compute ----
// No per-thread runtime-indexed arrays: srcdst slice is read twice (L2-hot).
__global__ void __launch_bounds__(256)
bucket_kernel(const float4* __restrict__ x,
              const int* __restrict__ srcdst,
              const int* __restrict__ excl, const int* __restrict__ btot,
              const float* __restrict__ We1, const float* __restrict__ be1,
              const float* __restrict__ Wn11,    // row 0 used
              const float* __restrict__ C, const float* __restrict__ bp,
              const float* __restrict__ Wn12, const float* __restrict__ bn12,
              const float* __restrict__ Wn21, const float* __restrict__ bn21,
              const float* __restrict__ Wn22, const float* __restrict__ bn22,
              float* __restrict__ x_out, int N, int E)
{
    __shared__ float sWe1t[HD*4];       // [j][i]
    __shared__ float sCt[HD*16];        // [j][k] padded
    __shared__ float sbe1[HD], sW11[HD], sbp[HD];
    __shared__ float sW12[HD*HD], sb12[HD];
    __shared__ float sW21[(1+HD)*HD], sb21[HD], sW22[HD*HD], sb22[HD];
    __shared__ float4 xn[WNODE];
    __shared__ float nf2[WNODE];
    __shared__ int hist[WNODE];
    __shared__ int cursor[WNODE];
    __shared__ int sorted[TILE];

    int tid = threadIdx.x;

    if (tid < HD*4) {                       // sWe1t[j*4+i] = We1[i*HD+j]
        int j = tid >> 2, i = tid & 3;
        sWe1t[tid] = We1[i*HD + j];
    }
    for (int t = tid; t < HD*16; t += 256) {
        int j = t >> 4, k = t & 15;
        sCt[t] = (k < HD) ? C[k*HD + j] : 0.f;
    }
    stage_f(sbe1, be1, HD);  stage_f(sW11, Wn11, HD);  stage_f(sbp, bp, HD);
    stage_f(sW12, Wn12, HD*HD); stage_f(sb12, bn12, HD);
    stage_f(sW21, Wn21, (1+HD)*HD); stage_f(sb21, bn21, HD);
    stage_f(sW22, Wn22, HD*HD); stage_f(sb22, bn22, HD);

    int b = blockIdx.x;
    int nb0 = b * WNODE;
    int nN = min(WNODE, N - nb0);

    if (tid < nN) {
        float4 v = x[nb0 + tid];
        xn[tid] = v;
        float ip = -v.x*v.x + v.y*v.y + v.z*v.z + v.w*v.w;
        nf2[tid] = psi_f(ip);
    }

    int c0 = b * NBLKA;
    int lo = excl[c0] + btot[c0 >> 11];
    int hi;
    if (b + 1 < NBIN) { int c1 = (b + 1) * NBLKA; hi = excl[c1] + btot[c1 >> 11]; }
    else hi = E;

    float acc[HD];
    #pragma unroll
    for (int j = 0; j < HD; ++j) acc[j] = 0.f;
    int deg = 0;

    __syncthreads();

    for (int tb = lo; tb < hi; tb += TILE) {
        int tsz = min(TILE, hi - tb);

        hist[tid] = 0;
        __syncthreads();

        // pass 1: count
        for (int o = tid; o < tsz; o += 256) {
            int p = srcdst[tb + o];
            atomicAdd(&hist[(p >> 18) & 255], 1);
        }
        __syncthreads();

        // inclusive scan -> cursor, then convert to exclusive base
        cursor[tid] = hist[tid];
        __syncthreads();
        for (int st = 1; st < 256; st <<= 1) {
            int v = (tid >= st) ? cursor[tid - st] : 0;
            __syncthreads();
            cursor[tid] += v;
            __syncthreads();
        }
        int exb = cursor[tid] - hist[tid];
        __syncthreads();
        cursor[tid] = exb;
        __syncthreads();

        // pass 2: scatter into sorted[]
        for (int o = tid; o < tsz; o += 256) {
            int p = srcdst[tb + o];
            int pos = atomicAdd(&cursor[(p >> 18) & 255], 1);
            sorted[pos] = p;
        }
        __syncthreads();

        // phase 2: thread tid == node tid, serial over its contiguous run
        int cntt = hist[tid];
        if (cntt > 0) {
            int start = cursor[tid] - cntt;   // cursor is now inclusive end
            float4 bx = xn[tid];
            float f2 = nf2[tid];

            float4 a = x[sorted[start] & 262143];
            for (int i = 0; i < cntt; ++i) {
                float4 an = a;
                if (i + 1 < cntt) an = x[sorted[start + i + 1] & 262143];

                float f0 = -a.x*a.x + a.y*a.y + a.z*a.z + a.w*a.w;
                float f1 = -a.x*bx.x + a.y*bx.y + a.z*bx.z + a.w*bx.w;
                float dx = a.x-bx.x, dy = a.y-bx.y, dz = a.z-bx.z, dw = a.w-bx.w;
                float f3 = psi_f(-dx*dx + dy*dy + dz*dz + dw*dw);

                float h1[HD];
                #pragma unroll
                for (int j = 0; j < HD; ++j) {
                    float v = f0*sWe1t[j*4+0] + f1*sWe1t[j*4+1] + f2*sWe1t[j*4+2] + f3*sWe1t[j*4+3] + sbe1[j];
                    h1[j] = fmaxf(v, 0.f);
                }
                #pragma unroll
                for (int j = 0; j < HD; ++j) {
                    float v = fmaf(f0, sW11[j], sbp[j]);
                    #pragma unroll
                    for (int k2 = 0; k2 < HD; ++k2) v = fmaf(h1[k2], sCt[j*16+k2], v);
                    acc[j] += fmaxf(v, 0.f);
                }
                a = an;
            }
            deg += cntt;
        }
        __syncthreads();
    }

    // finalize node tid
    if (tid < nN) {
        float aggm[HD];
        if (deg > 0) {
            float inv = 1.0f / (float)deg;
            float am[HD];
            #pragma unroll
            for (int k = 0; k < HD; ++k) am[k] = acc[k] * inv;
            #pragma unroll
            for (int j = 0; j < HD; ++j) {
                float v = sb12[j];
                #pragma unroll
                for (int k = 0; k < HD; ++k) v = fmaf(am[k], sW12[k*HD+j], v);
                aggm[j] = v;
            }
        } else {
            #pragma unroll
            for (int j = 0; j < HD; ++j) aggm[j] = 0.f;
        }

        float4 v4 = xn[tid];
        float ipbb = -v4.x*v4.x + v4.y*v4.y + v4.z*v4.z + v4.w*v4.w;
        float h[HD];
        #pragma unroll
        for (int j = 0; j < HD; ++j) {
            float v = fmaf(ipbb, sW21[j], sb21[j]);
            #pragma unroll
            for (int k = 0; k < HD; ++k) v = fmaf(aggm[k], sW21[(1+k)*HD+j], v);
            h[j] = fmaxf(v, 0.f);
        }
        float xo[16];
        #pragma unroll
        for (int j = 0; j < HD; ++j) {
            float v = sb22[j];
            #pragma unroll
            for (int k = 0; k < HD; ++k) v = fmaf(h[k], sW22[k*HD+j], v);
            xo[j] = v;
        }
        float4* op = (float4*)(x_out + (size_t)(nb0 + tid) * 16);
        op[0] = make_float4(xo[0], xo[1], xo[2], xo[3]);
        op[1] = make_float4(xo[4], xo[5], xo[6], xo[7]);
        op[2] = make_float4(xo[8], xo[9], xo[10], xo[11]);
        op[3] = make_float4(xo[12], xo[13], 0.f, 0.f);
    }
}

// ---- pass 4: per-graph mean + global MLP ----
__global__ void __launch_bounds__(256)
graph_kernel(const float* __restrict__ x_out, const int* __restrict__ batch,
             const float* __restrict__ Wg1, const float* __restrict__ bg1,
             const float* __restrict__ Wg2, const float* __restrict__ bg2,
             float* __restrict__ out, int N, int G)
{
    __shared__ float red[256 * 15];
    int g = blockIdx.x;
    int tid = threadIdx.x;

    int lo = lower_bound_i(batch, N, g);
    int hi = lower_bound_i(batch, N, g + 1);

    float acc[HD];
    #pragma unroll
    for (int j = 0; j < HD; ++j) acc[j] = 0.f;

    for (int n = lo + tid; n < hi; n += 256) {
        const float* xp = x_out + (size_t)n * 16;
        #pragma unroll
        for (int j = 0; j < HD; ++j) acc[j] += xp[j];
    }
    #pragma unroll
    for (int j = 0; j < HD; ++j) red[tid * 15 + j] = acc[j];
    __syncthreads();

    for (int s = 128; s >= 1; s >>= 1) {
        if (tid < s) {
            #pragma unroll
            for (int j = 0; j < HD; ++j) red[tid * 15 + j] += red[(tid + s) * 15 + j];
        }
        __syncthreads();
    }

    if (tid == 0) {
        float invc = 1.0f / fmaxf((float)(hi - lo), 1.0f);
        float gm[HD];
        #pragma unroll
        for (int j = 0; j < HD; ++j) gm[j] = red[j] * invc;
        float h[HD];
        #pragma unroll
        for (int j = 0; j < HD; ++j) {
            float v = bg1[j];
            #pragma unroll
            for (int k = 0; k < HD; ++k) v = fmaf(gm[k], Wg1[k*HD+j], v);
            h[j] = fmaxf(v, 0.f);
        }
        #pragma unroll
        for (int o = 0; o < NOUT; ++o) {
            float v = bg2[o];
            #pragma unroll
            for (int k = 0; k < HD; ++k) v = fmaf(h[k], Wg2[k*NOUT+o], v);
            out[g * NOUT + o] = v;
        }
    }
}

extern "C" void kernel_launch(void* const* d_in, const int* in_sizes, int n_in,
                              void* d_out, int out_size, void* d_ws, size_t ws_size,
                              hipStream_t stream) {
    const int N = NN, E = EE, G = GG;

    const float4* x     = (const float4*)d_in[0];
    const int*    eidx  = (const int*)d_in[1];
    const int*    batch = (const int*)d_in[2];
    const float*  We1  = (const float*)d_in[3];
    const float*  be1  = (const float*)d_in[4];
    const float*  We2  = (const float*)d_in[5];
    const float*  be2  = (const float*)d_in[6];
    const float*  Wn11 = (const float*)d_in[7];
    const float*  bn11 = (const float*)d_in[8];
    const float*  Wn12 = (const float*)d_in[9];
    const float*  bn12 = (const float*)d_in[10];
    const float*  Wn21 = (const float*)d_in[11];
    const float*  bn21 = (const float*)d_in[12];
    const float*  Wn22 = (const float*)d_in[13];
    const float*  bn22 = (const float*)d_in[14];
    const float*  Wg1  = (const float*)d_in[15];
    const float*  bg1  = (const float*)d_in[16];
    const float*  Wg2  = (const float*)d_in[17];
    const float*  bg2  = (const float*)d_in[18];

    const int* row = eidx;       // edge_index[0]
    const int* col = eidx + E;   // edge_index[1]

    // workspace layout (bytes) — every buffer fully written before read, no memsets:
    //   ghist  @ 0          NCELL ints  (800,768)
    //   excl   @ 1,048,576  NCELL ints  (800,768)
    //   btot   @ 1,900,544  NBSCAN ints (392)
    //   Cfold  @ 1,901,568  (784)
    //   bfold  @ 1,902,592  (56)
    //   srcdst @ 2,097,152  E ints      (12,800,000) -> ends 14,897,152
    //   x_out  @ 14,897,152 N*16 floats (12,800,000) -> ends 27,697,152
    char*  ws     = (char*)d_ws;
    int*   ghist  = (int*)(ws + 0);
    int*   excl   = (int*)(ws + 1048576);
    int*   btot   = (int*)(ws + 1900544);
    float* Cfold  = (float*)(ws + 1901568);
    float* bfold  = (float*)(ws + 1902592);
    int*   srcdst = (int*)(ws + 2097152);
    float* x_out  = (float*)(ws + 14897152);

    dim3 blk(256);
    fold_kernel<<<dim3(1), blk, 0, stream>>>(We2, be2, Wn11, bn11, Cfold, bfold);

    histA<<<dim3(NBLKA), blk, 0, stream>>>(col, ghist);
    scan1_kernel<<<dim3(NBSCAN), dim3(SBS), 0, stream>>>(ghist, excl, btot, NCELL);
    scan2_kernel<<<dim3(1), blk, 0, stream>>>(btot, NBSCAN);
    scatterA<<<dim3(NBLKA), blk, 0, stream>>>(row, col, excl, btot, srcdst);

    bucket_kernel<<<dim3(NBIN), blk, 0, stream>>>(
        x, srcdst, excl, btot,
        We1, be1, Wn11, Cfold, bfold,
        Wn12, bn12, Wn21, bn21, Wn22, bn22,
        x_out, N, E);

    graph_kernel<<<dim3(G), blk, 0, stream>>>(x_out, batch, Wg1, bg1, Wg2, bg2,
                                              (float*)d_out, N, G);
}

// Round 8
// 207.528 us; speedup vs baseline: 6.7031x; 1.3590x over previous
//
#include <hip/hip_runtime.h>

#define HD 14
#define NOUT 2
#define NN 200000
#define EE 3200000
#define GG 2000

// bucket config
#define WNODE 256                         // nodes per bucket (c >> 8)
#define NBIN 782                          // ceil(200000/256)
#define NBLKA 256                         // partition blocks
#define EPERA 12500                       // edges per partition block
#define NCELL (NBIN*NBLKA)                // 200192
#define TILE 4096                         // edges per in-block sort tile

// scan config
#define SBS 256
#define SEL 8
#define CHUNK (SBS*SEL)                   // 2048
#define NBSCAN ((NCELL + CHUNK - 1) / CHUNK)  // 98

__device__ __forceinline__ float psi_f(float v) {
    float r = log1pf(fabsf(v));
    return v < 0.f ? -r : r;
}

__device__ __forceinline__ int lower_bound_i(const int* a, int n, int key) {
    int lo = 0, hi = n;
    while (lo < hi) { int mid = (lo + hi) >> 1; if (a[mid] < key) lo = mid + 1; else hi = mid; }
    return lo;
}

// ---- pass 0: fold We2 into Wn11 ----
__global__ void __launch_bounds__(256)
fold_kernel(const float* __restrict__ We2, const float* __restrict__ be2,
            const float* __restrict__ Wn11, const float* __restrict__ bn11,
            float* __restrict__ C, float* __restrict__ bp)
{
    int t = threadIdx.x;
    if (t < HD*HD) {
        int k = t / HD, j = t % HD;
        float s = 0.f;
        #pragma unroll
        for (int u = 0; u < HD; ++u) s = fmaf(We2[k*HD+u], Wn11[(1+u)*HD+j], s);
        C[t] = s;
    } else if (t < HD*HD + HD) {
        int j = t - HD*HD;
        float s = bn11[j];
        #pragma unroll
        for (int u = 0; u < HD; ++u) s = fmaf(be2[u], Wn11[(1+u)*HD+j], s);
        bp[j] = s;
    }
}

// ---- pass 1: per-(bucket, block) histogram of col>>8, bin-major output ----
__global__ void __launch_bounds__(256)
histA(const int* __restrict__ col, int* __restrict__ ghist)
{
    __shared__ int hist[NBIN];
    int tid = threadIdx.x;
    for (int i = tid; i < NBIN; i += 256) hist[i] = 0;
    __syncthreads();
    int j = blockIdx.x;
    int base = j * EPERA;
    for (int it = 0; it < EPERA; it += 256) {
        int o = it + tid;
        if (o < EPERA) atomicAdd(&hist[col[base + o] >> 8], 1);
    }
    __syncthreads();
    for (int i = tid; i < NBIN; i += 256) ghist[i * NBLKA + j] = hist[i];
}

// ---- scan of ghist[NCELL] -> excl (chunk-local) + btot (chunk bases) ----
__global__ void __launch_bounds__(SBS)
scan1_kernel(const int* __restrict__ cnt, int* __restrict__ excl,
             int* __restrict__ btot, int n)
{
    __shared__ int lds[SBS];
    int tid = threadIdx.x;
    int base = blockIdx.x * CHUNK + tid * SEL;
    int v[SEL]; int s = 0;
    #pragma unroll
    for (int k = 0; k < SEL; ++k) { int i = base + k; v[k] = (i < n) ? cnt[i] : 0; s += v[k]; }
    lds[tid] = s; __syncthreads();
    for (int off = 1; off < SBS; off <<= 1) {
        int t = (tid >= off) ? lds[tid - off] : 0;
        __syncthreads();
        lds[tid] += t;
        __syncthreads();
    }
    int incl = lds[tid];
    int run = incl - s;
    if (tid == SBS - 1) btot[blockIdx.x] = incl;
    #pragma unroll
    for (int k = 0; k < SEL; ++k) { int i = base + k; if (i < n) excl[i] = run; run += v[k]; }
}

__global__ void __launch_bounds__(256)
scan2_kernel(int* __restrict__ btot, int nb)
{
    __shared__ int lds[256];
    int tid = threadIdx.x;
    int v = (tid < nb) ? btot[tid] : 0;
    lds[tid] = v; __syncthreads();
    for (int off = 1; off < 256; off <<= 1) {
        int t = (tid >= off) ? lds[tid - off] : 0;
        __syncthreads();
        lds[tid] += t;
        __syncthreads();
    }
    if (tid < nb) btot[tid] = lds[tid] - v;   // exclusive chunk bases, in place
}

// ---- pass 2: partition edges into buckets, packed (src | dl<<18) ----
__global__ void __launch_bounds__(256)
scatterA(const int* __restrict__ row, const int* __restrict__ col,
         const int* __restrict__ excl, const int* __restrict__ btot,
         int* __restrict__ srcdst)
{
    __shared__ int lcount[NBIN];
    int tid = threadIdx.x;
    for (int i = tid; i < NBIN; i += 256) lcount[i] = 0;
    __syncthreads();
    int j = blockIdx.x;
    int base = j * EPERA;
    for (int it = 0; it < EPERA; it += 256) {
        int o = it + tid;
        if (o < EPERA) {
            int e = base + o;
            int c = col[e];
            int r = row[e];
            int bb = c >> 8;
            int dl = c & 255;
            int rk = atomicAdd(&lcount[bb], 1);
            int cell = bb * NBLKA + j;
            int pos = excl[cell] + btot[cell >> 11] + rk;
            srcdst[pos] = r | (dl << 18);
        }
    }
}

// ---- pass 3: per-bucket tile counting-sort + edge-parallel compute +
//              wave-segmented reduction (scalar-pipe weights, no LDS weights) ----
__global__ void __launch_bounds__(256)
bucket_kernel(const float4* __restrict__ x,
              const int* __restrict__ srcdst,
              const int* __restrict__ excl, const int* __restrict__ btot,
              const float* __restrict__ We1, const float* __restrict__ be1,
              const float* __restrict__ Wn11,    // row 0 used
              const float* __restrict__ C, const float* __restrict__ bp,
              const float* __restrict__ Wn12, const float* __restrict__ bn12,
              const float* __restrict__ Wn21, const float* __restrict__ bn21,
              const float* __restrict__ Wn22, const float* __restrict__ bn22,
              float* __restrict__ x_out, int N, int E)
{
    __shared__ float4 xn[WNODE];
    __shared__ float nf2[WNODE];
    __shared__ float aggs[WNODE * 15];
    __shared__ int hist[WNODE];
    __shared__ int cursor[WNODE];
    __shared__ int degs[WNODE];
    __shared__ int sorted[TILE];

    int tid = threadIdx.x;
    int lane = tid & 63;
    int wv = tid >> 6;

    int b = blockIdx.x;
    int nb0 = b * WNODE;
    int nN = min(WNODE, N - nb0);

    degs[tid] = 0;
    for (int i = tid; i < WNODE * 15; i += 256) aggs[i] = 0.f;

    if (tid < nN) {
        float4 v = x[nb0 + tid];
        xn[tid] = v;
        nf2[tid] = psi_f(-v.x*v.x + v.y*v.y + v.z*v.z + v.w*v.w);
    }

    int c0 = b * NBLKA;
    int lo = excl[c0] + btot[c0 >> 11];
    int hi;
    if (b + 1 < NBIN) { int c1 = (b + 1) * NBLKA; hi = excl[c1] + btot[c1 >> 11]; }
    else hi = E;

    __syncthreads();

    for (int tb = lo; tb < hi; tb += TILE) {
        int tsz = min(TILE, hi - tb);

        hist[tid] = 0;
        __syncthreads();

        // count
        for (int o = tid; o < tsz; o += 256) {
            int p = srcdst[tb + o];
            atomicAdd(&hist[(p >> 18) & 255], 1);
        }
        __syncthreads();

        // scan -> exclusive cursor; accumulate degree
        cursor[tid] = hist[tid];
        __syncthreads();
        for (int st = 1; st < 256; st <<= 1) {
            int v = (tid >= st) ? cursor[tid - st] : 0;
            __syncthreads();
            cursor[tid] += v;
            __syncthreads();
        }
        int exb = cursor[tid] - hist[tid];
        degs[tid] += hist[tid];
        __syncthreads();
        cursor[tid] = exb;
        __syncthreads();

        // scatter into sorted[]
        for (int o = tid; o < tsz; o += 256) {
            int p = srcdst[tb + o];
            int pos = atomicAdd(&cursor[(p >> 18) & 255], 1);
            sorted[pos] = p;
        }
        __syncthreads();

        // edge-parallel compute + wave-segmented reduction
        for (int cb = wv * 64; cb < tsz; cb += 256) {
            int o = cb + lane;
            bool valid = (o < tsz);
            int p = valid ? sorted[o] : 0;
            int nid = valid ? ((p >> 18) & 255) : 256;   // sentinel for tail lanes

            float h2v[HD];
            if (valid) {
                float4 a = x[p & 262143];
                float4 bx = xn[nid];
                float f2 = nf2[nid];

                float f0 = -a.x*a.x + a.y*a.y + a.z*a.z + a.w*a.w;
                float f1 = -a.x*bx.x + a.y*bx.y + a.z*bx.z + a.w*bx.w;
                float dx = a.x-bx.x, dy = a.y-bx.y, dz = a.z-bx.z, dw = a.w-bx.w;
                float f3 = psi_f(-dx*dx + dy*dy + dz*dz + dw*dw);

                float h1[HD];
                #pragma unroll
                for (int j = 0; j < HD; ++j) {
                    float v = f0*We1[j] + f1*We1[HD+j] + f2*We1[2*HD+j] + f3*We1[3*HD+j] + be1[j];
                    h1[j] = fmaxf(v, 0.f);
                }
                #pragma unroll
                for (int j = 0; j < HD; ++j) {
                    float v = fmaf(f0, Wn11[j], bp[j]);
                    #pragma unroll
                    for (int k = 0; k < HD; ++k) v = fmaf(h1[k], C[k*HD+j], v);
                    h2v[j] = fmaxf(v, 0.f);
                }
            } else {
                #pragma unroll
                for (int j = 0; j < HD; ++j) h2v[j] = 0.f;
            }

            // segmented inclusive sum over non-decreasing nid within the wave
            #pragma unroll
            for (int st = 1; st < 64; st <<= 1) {
                int nup = __shfl_up(nid, st, 64);
                bool take = (lane >= st) && (nup == nid);
                #pragma unroll
                for (int j = 0; j < HD; ++j) {
                    float v = __shfl_up(h2v[j], st, 64);
                    h2v[j] += take ? v : 0.f;
                }
            }
            int ndn = __shfl_down(nid, 1, 64);
            bool lastseg = valid && (lane == 63 || ndn != nid);
            if (lastseg) {
                #pragma unroll
                for (int j = 0; j < HD; ++j) atomicAdd(&aggs[nid * 15 + j], h2v[j]);
            }
        }
        __syncthreads();
    }

    // finalize node tid (scalar-pipe weights)
    if (tid < nN) {
        int deg = degs[tid];
        float aggm[HD];
        if (deg > 0) {
            float inv = 1.0f / (float)deg;
            float am[HD];
            #pragma unroll
            for (int k = 0; k < HD; ++k) am[k] = aggs[tid * 15 + k] * inv;
            #pragma unroll
            for (int j = 0; j < HD; ++j) {
                float v = bn12[j];
                #pragma unroll
                for (int k = 0; k < HD; ++k) v = fmaf(am[k], Wn12[k*HD+j], v);
                aggm[j] = v;
            }
        } else {
            #pragma unroll
            for (int j = 0; j < HD; ++j) aggm[j] = 0.f;
        }

        float4 v4 = xn[tid];
        float ipbb = -v4.x*v4.x + v4.y*v4.y + v4.z*v4.z + v4.w*v4.w;
        float h[HD];
        #pragma unroll
        for (int j = 0; j < HD; ++j) {
            float v = fmaf(ipbb, Wn21[j], bn21[j]);
            #pragma unroll
            for (int k = 0; k < HD; ++k) v = fmaf(aggm[k], Wn21[(1+k)*HD+j], v);
            h[j] = fmaxf(v, 0.f);
        }
        float xo[16];
        #pragma unroll
        for (int j = 0; j < HD; ++j) {
            float v = bn22[j];
            #pragma unroll
            for (int k = 0; k < HD; ++k) v = fmaf(h[k], Wn22[k*HD+j], v);
            xo[j] = v;
        }
        float4* op = (float4*)(x_out + (size_t)(nb0 + tid) * 16);
        op[0] = make_float4(xo[0], xo[1], xo[2], xo[3]);
        op[1] = make_float4(xo[4], xo[5], xo[6], xo[7]);
        op[2] = make_float4(xo[8], xo[9], xo[10], xo[11]);
        op[3] = make_float4(xo[12], xo[13], 0.f, 0.f);
    }
}

// ---- pass 4: per-graph mean + global MLP ----
__global__ void __launch_bounds__(256)
graph_kernel(const float* __restrict__ x_out, const int* __restrict__ batch,
             const float* __restrict__ Wg1, const float* __restrict__ bg1,
             const float* __restrict__ Wg2, const float* __restrict__ bg2,
             float* __restrict__ out, int N, int G)
{
    __shared__ float red[256 * 15];
    int g = blockIdx.x;
    int tid = threadIdx.x;

    int lo = lower_bound_i(batch, N, g);
    int hi = lower_bound_i(batch, N, g + 1);

    float acc[HD];
    #pragma unroll
    for (int j = 0; j < HD; ++j) acc[j] = 0.f;

    for (int n = lo + tid; n < hi; n += 256) {
        const float* xp = x_out + (size_t)n * 16;
        #pragma unroll
        for (int j = 0; j < HD; ++j) acc[j] += xp[j];
    }
    #pragma unroll
    for (int j = 0; j < HD; ++j) red[tid * 15 + j] = acc[j];
    __syncthreads();

    for (int s = 128; s >= 1; s >>= 1) {
        if (tid < s) {
            #pragma unroll
            for (int j = 0; j < HD; ++j) red[tid * 15 + j] += red[(tid + s) * 15 + j];
        }
        __syncthreads();
    }

    if (tid == 0) {
        float invc = 1.0f / fmaxf((float)(hi - lo), 1.0f);
        float gm[HD];
        #pragma unroll
        for (int j = 0; j < HD; ++j) gm[j] = red[j] * invc;
        float h[HD];
        #pragma unroll
        for (int j = 0; j < HD; ++j) {
            float v = bg1[j];
            #pragma unroll
            for (int k = 0; k < HD; ++k) v = fmaf(gm[k], Wg1[k*HD+j], v);
            h[j] = fmaxf(v, 0.f);
        }
        #pragma unroll
        for (int o = 0; o < NOUT; ++o) {
            float v = bg2[o];
            #pragma unroll
            for (int k = 0; k < HD; ++k) v = fmaf(h[k], Wg2[k*NOUT+o], v);
            out[g * NOUT + o] = v;
        }
    }
}

extern "C" void kernel_launch(void* const* d_in, const int* in_sizes, int n_in,
                              void* d_out, int out_size, void* d_ws, size_t ws_size,
                              hipStream_t stream) {
    const int N = NN, E = EE, G = GG;

    const float4* x     = (const float4*)d_in[0];
    const int*    eidx  = (const int*)d_in[1];
    const int*    batch = (const int*)d_in[2];
    const float*  We1  = (const float*)d_in[3];
    const float*  be1  = (const float*)d_in[4];
    const float*  We2  = (const float*)d_in[5];
    const float*  be2  = (const float*)d_in[6];
    const float*  Wn11 = (const float*)d_in[7];
    const float*  bn11 = (const float*)d_in[8];
    const float*  Wn12 = (const float*)d_in[9];
    const float*  bn12 = (const float*)d_in[10];
    const float*  Wn21 = (const float*)d_in[11];
    const float*  bn21 = (const float*)d_in[12];
    const float*  Wn22 = (const float*)d_in[13];
    const float*  bn22 = (const float*)d_in[14];
    const float*  Wg1  = (const float*)d_in[15];
    const float*  bg1  = (const float*)d_in[16];
    const float*  Wg2  = (const float*)d_in[17];
    const float*  bg2  = (const float*)d_in[18];

    const int* row = eidx;       // edge_index[0]
    const int* col = eidx + E;   // edge_index[1]

    // workspace layout (bytes) — every buffer fully written before read, no memsets:
    //   ghist  @ 0          NCELL ints  (800,768)
    //   excl   @ 1,048,576  NCELL ints  (800,768)
    //   btot   @ 1,900,544  NBSCAN ints (392)
    //   Cfold  @ 1,901,568  (784)
    //   bfold  @ 1,902,592  (56)
    //   srcdst @ 2,097,152  E ints      (12,800,000) -> ends 14,897,152
    //   x_out  @ 14,897,152 N*16 floats (12,800,000) -> ends 27,697,152
    char*  ws     = (char*)d_ws;
    int*   ghist  = (int*)(ws + 0);
    int*   excl   = (int*)(ws + 1048576);
    int*   btot   = (int*)(ws + 1900544);
    float* Cfold  = (float*)(ws + 1901568);
    float* bfold  = (float*)(ws + 1902592);
    int*   srcdst = (int*)(ws + 2097152);
    float* x_out  = (float*)(ws + 14897152);

    dim3 blk(256);
    fold_kernel<<<dim3(1), blk, 0, stream>>>(We2, be2, Wn11, bn11, Cfold, bfold);

    histA<<<dim3(NBLKA), blk, 0, stream>>>(col, ghist);
    scan1_kernel<<<dim3(NBSCAN), dim3(SBS), 0, stream>>>(ghist, excl, btot, NCELL);
    scan2_kernel<<<dim3(1), blk, 0, stream>>>(btot, NBSCAN);
    scatterA<<<dim3(NBLKA), blk, 0, stream>>>(row, col, excl, btot, srcdst);

    bucket_kernel<<<dim3(NBIN), blk, 0, stream>>>(
        x, srcdst, excl, btot,
        We1, be1, Wn11, Cfold, bfold,
        Wn12, bn12, Wn21, bn21, Wn22, bn22,
        x_out, N, E);

    graph_kernel<<<dim3(G), blk, 0, stream>>>(x_out, batch, Wg1, bg1, Wg2, bg2,
                                              (float*)d_out, N, G);
}

// Round 10
// 177.683 us; speedup vs baseline: 7.8290x; 1.1680x over previous
//
#include <hip/hip_runtime.h>

#define HD 14
#define NOUT 2
#define NN 200000
#define EE 3200000
#define GG 2000

// bucket config
#define WNODE 128                         // nodes per bucket (c >> 7)
#define NBIN 1563                         // ceil(200000/128)
#define NBLKA 256                         // partition blocks
#define EPERA 12500                       // edges per partition block
#define NCELL (NBIN*NBLKA)                // 400128
#define TILE 2048                         // edges per in-block sort tile

// scan config
#define SBS 256
#define SEL 8
#define CHUNK (SBS*SEL)                   // 2048
#define NBSCAN ((NCELL + CHUNK - 1) / CHUNK)  // 196

typedef __fp16 hv2 __attribute__((ext_vector_type(2)));
union HU { hv2 h; __fp16 f[2]; unsigned u; int i; };
__device__ __forceinline__ hv2 as_h2(unsigned u) { HU x; x.u = u; return x.h; }

__device__ __forceinline__ float psi_f(float v) {
    float r = __logf(1.0f + fabsf(v));
    return __builtin_copysignf(r, v);
}

__device__ __forceinline__ int lower_bound_i(const int* a, int n, int key) {
    int lo = 0, hi = n;
    while (lo < hi) { int mid = (lo + hi) >> 1; if (a[mid] < key) lo = mid + 1; else hi = mid; }
    return lo;
}

// ---- pass 0: fold We2 into Wn11; emit f16-packed weight pairs ----
__global__ void __launch_bounds__(256)
fold_kernel(const float* __restrict__ We1,
            const float* __restrict__ We2, const float* __restrict__ be2,
            const float* __restrict__ Wn11, const float* __restrict__ bn11,
            float* __restrict__ bp, unsigned* __restrict__ We1pk,
            unsigned* __restrict__ Cpk)
{
    __shared__ float sC[HD*HD];
    int t = threadIdx.x;
    if (t < HD*HD) {
        int k = t / HD, j = t % HD;
        float s = 0.f;
        #pragma unroll
        for (int u = 0; u < HD; ++u) s = fmaf(We2[k*HD+u], Wn11[(1+u)*HD+j], s);
        sC[t] = s;
    } else if (t < HD*HD + HD) {
        int j = t - HD*HD;
        float s = bn11[j];
        #pragma unroll
        for (int u = 0; u < HD; ++u) s = fmaf(be2[u], Wn11[(1+u)*HD+j], s);
        bp[j] = s;
    }
    __syncthreads();
    if (t < 7*HD) {                      // Cpk[tt*14+j] = pack(C[2tt][j], C[2tt+1][j])
        int tt = t / HD, j = t % HD;
        HU x; x.h = __builtin_amdgcn_cvt_pkrtz(sC[(2*tt)*HD + j], sC[(2*tt+1)*HD + j]);
        Cpk[t] = x.u;
    } else if (t < 7*HD + 2*HD) {        // We1pk[tt*14+j] = pack(We1[2tt][j], We1[2tt+1][j])
        int q = t - 7*HD;
        int tt = q / HD, j = q % HD;
        HU x; x.h = __builtin_amdgcn_cvt_pkrtz(We1[(2*tt)*HD + j], We1[(2*tt+1)*HD + j]);
        We1pk[q] = x.u;
    }
}

// ---- pass 1: per-(bucket, block) histogram of col>>7, bin-major output ----
__global__ void __launch_bounds__(256)
histA(const int* __restrict__ col, int* __restrict__ ghist)
{
    __shared__ int hist[NBIN];
    int tid = threadIdx.x;
    for (int i = tid; i < NBIN; i += 256) hist[i] = 0;
    __syncthreads();
    int j = blockIdx.x;
    int base = j * EPERA;
    for (int it = 0; it < EPERA; it += 256) {
        int o = it + tid;
        if (o < EPERA) atomicAdd(&hist[col[base + o] >> 7], 1);
    }
    __syncthreads();
    for (int i = tid; i < NBIN; i += 256) ghist[i * NBLKA + j] = hist[i];
}

// ---- scan of ghist[NCELL] -> excl (chunk-local) + btot (chunk bases) ----
__global__ void __launch_bounds__(SBS)
scan1_kernel(const int* __restrict__ cnt, int* __restrict__ excl,
             int* __restrict__ btot, int n)
{
    __shared__ int lds[SBS];
    int tid = threadIdx.x;
    int base = blockIdx.x * CHUNK + tid * SEL;
    int v[SEL]; int s = 0;
    #pragma unroll
    for (int k = 0; k < SEL; ++k) { int i = base + k; v[k] = (i < n) ? cnt[i] : 0; s += v[k]; }
    lds[tid] = s; __syncthreads();
    for (int off = 1; off < SBS; off <<= 1) {
        int t = (tid >= off) ? lds[tid - off] : 0;
        __syncthreads();
        lds[tid] += t;
        __syncthreads();
    }
    int incl = lds[tid];
    int run = incl - s;
    if (tid == SBS - 1) btot[blockIdx.x] = incl;
    #pragma unroll
    for (int k = 0; k < SEL; ++k) { int i = base + k; if (i < n) excl[i] = run; run += v[k]; }
}

__global__ void __launch_bounds__(256)
scan2_kernel(int* __restrict__ btot, int nb)
{
    __shared__ int lds[256];
    int tid = threadIdx.x;
    int v = (tid < nb) ? btot[tid] : 0;
    lds[tid] = v; __syncthreads();
    for (int off = 1; off < 256; off <<= 1) {
        int t = (tid >= off) ? lds[tid - off] : 0;
        __syncthreads();
        lds[tid] += t;
        __syncthreads();
    }
    if (tid < nb) btot[tid] = lds[tid] - v;   // exclusive chunk bases, in place
}

// ---- pass 2: partition edges into buckets, packed (src | dl<<18) ----
__global__ void __launch_bounds__(256)
scatterA(const int* __restrict__ row, const int* __restrict__ col,
         const int* __restrict__ excl, const int* __restrict__ btot,
         int* __restrict__ srcdst)
{
    __shared__ int lcount[NBIN];
    int tid = threadIdx.x;
    for (int i = tid; i < NBIN; i += 256) lcount[i] = 0;
    __syncthreads();
    int j = blockIdx.x;
    int base = j * EPERA;
    for (int it = 0; it < EPERA; it += 256) {
        int o = it + tid;
        if (o < EPERA) {
            int e = base + o;
            int c = col[e];
            int r = row[e];
            int bb = c >> 7;
            int dl = c & 127;
            int rk = atomicAdd(&lcount[bb], 1);
            int cell = bb * NBLKA + j;
            int pos = excl[cell] + btot[cell >> 11] + rk;
            srcdst[pos] = r | (dl << 18);
        }
    }
}

// ---- pass 3: per-bucket tile counting-sort + edge-parallel fdot2 compute +
//              f16-packed wave-segmented reduction ----
__global__ void __launch_bounds__(256)
bucket_kernel(const float4* __restrict__ x,
              const int* __restrict__ srcdst,
              const int* __restrict__ excl, const int* __restrict__ btot,
              const unsigned* __restrict__ We1pk, const float* __restrict__ be1,
              const float* __restrict__ Wn11,    // row 0 used
              const unsigned* __restrict__ Cpk, const float* __restrict__ bp,
              const float* __restrict__ Wn12, const float* __restrict__ bn12,
              const float* __restrict__ Wn21, const float* __restrict__ bn21,
              const float* __restrict__ Wn22, const float* __restrict__ bn22,
              float* __restrict__ x_out, int N, int E)
{
    __shared__ float4 xn[WNODE];
    __shared__ float nf2[WNODE];
    __shared__ float aggs[WNODE * 15];
    __shared__ int hist[WNODE];
    __shared__ int cursor[WNODE];
    __shared__ int degs[WNODE];
    __shared__ int sorted[TILE];

    int tid = threadIdx.x;
    int lane = tid & 63;
    int wv = tid >> 6;

    int b = blockIdx.x;
    int nb0 = b * WNODE;
    int nN = min(WNODE, N - nb0);

    if (tid < WNODE) degs[tid] = 0;
    for (int i = tid; i < WNODE * 15; i += 256) aggs[i] = 0.f;

    if (tid < nN) {
        float4 v = x[nb0 + tid];
        xn[tid] = v;
        nf2[tid] = psi_f(-v.x*v.x + v.y*v.y + v.z*v.z + v.w*v.w);
    }

    int c0 = b * NBLKA;
    int lo = excl[c0] + btot[c0 >> 11];
    int hi;
    if (b + 1 < NBIN) { int c1 = (b + 1) * NBLKA; hi = excl[c1] + btot[c1 >> 11]; }
    else hi = E;

    __syncthreads();

    for (int tb = lo; tb < hi; tb += TILE) {
        int tsz = min(TILE, hi - tb);

        if (tid < WNODE) hist[tid] = 0;
        __syncthreads();

        // count
        for (int o = tid; o < tsz; o += 256) {
            int p = srcdst[tb + o];
            atomicAdd(&hist[p >> 18], 1);
        }
        __syncthreads();

        // inclusive scan over WNODE bins (first WNODE threads)
        if (tid < WNODE) cursor[tid] = hist[tid];
        __syncthreads();
        for (int st = 1; st < WNODE; st <<= 1) {
            int v = (tid >= st && tid < WNODE) ? cursor[tid - st] : 0;
            __syncthreads();
            if (tid < WNODE) cursor[tid] += v;
            __syncthreads();
        }
        if (tid < WNODE) {
            int exb = cursor[tid] - hist[tid];
            degs[tid] += hist[tid];
            cursor[tid] = exb;
        }
        __syncthreads();

        // scatter into sorted[]
        for (int o = tid; o < tsz; o += 256) {
            int p = srcdst[tb + o];
            int pos = atomicAdd(&cursor[p >> 18], 1);
            sorted[pos] = p;
        }
        __syncthreads();

        // edge-parallel compute + packed-f16 wave-segmented reduction
        for (int cb = wv * 64; cb < tsz; cb += 256) {
            int o = cb + lane;
            bool valid = (o < tsz);
            int p = valid ? sorted[o] : 0;
            int nid = valid ? (p >> 18) : WNODE;          // sentinel for tail lanes

            hv2 h2p[7];
            HU uz; uz.u = 0;
            #pragma unroll
            for (int t = 0; t < 7; ++t) h2p[t] = uz.h;

            if (valid) {
                float4 a = x[p & 262143];
                float4 bx = xn[nid];
                float f2 = nf2[nid];

                float f0 = -a.x*a.x + a.y*a.y + a.z*a.z + a.w*a.w;
                float f1 = -a.x*bx.x + a.y*bx.y + a.z*bx.z + a.w*bx.w;
                float dx = a.x-bx.x, dy = a.y-bx.y, dz = a.z-bx.z, dw = a.w-bx.w;
                float f3 = psi_f(-dx*dx + dy*dy + dz*dz + dw*dw);

                hv2 f01 = __builtin_amdgcn_cvt_pkrtz(f0, f1);
                hv2 f23 = __builtin_amdgcn_cvt_pkrtz(f2, f3);

                float h1[HD];
                #pragma unroll
                for (int j = 0; j < HD; ++j) {
                    float v = __builtin_amdgcn_fdot2(f23, as_h2(We1pk[HD + j]), be1[j], false);
                    v = __builtin_amdgcn_fdot2(f01, as_h2(We1pk[j]), v, false);
                    h1[j] = fmaxf(v, 0.f);
                }
                hv2 h1p[7];
                #pragma unroll
                for (int t = 0; t < 7; ++t) h1p[t] = __builtin_amdgcn_cvt_pkrtz(h1[2*t], h1[2*t+1]);

                float h2[HD];
                #pragma unroll
                for (int j = 0; j < HD; ++j) {
                    float v = fmaf(f0, Wn11[j], bp[j]);
                    #pragma unroll
                    for (int t = 0; t < 7; ++t) v = __builtin_amdgcn_fdot2(h1p[t], as_h2(Cpk[t*HD + j]), v, false);
                    h2[j] = fmaxf(v, 0.f);
                }
                #pragma unroll
                for (int t = 0; t < 7; ++t) h2p[t] = __builtin_amdgcn_cvt_pkrtz(h2[2*t], h2[2*t+1]);
            }

            // segmented inclusive sum over non-decreasing nid (packed f16 pairs)
            #pragma unroll
            for (int st = 1; st < 64; st <<= 1) {
                int nup = __shfl_up(nid, st, 64);
                bool take = (lane >= st) && (nup == nid);
                #pragma unroll
                for (int t = 0; t < 7; ++t) {
                    HU u; u.h = h2p[t];
                    u.i = __shfl_up(u.i, st, 64);
                    if (take) h2p[t] += u.h;
                }
            }
            int ndn = __shfl_down(nid, 1, 64);
            bool lastseg = valid && (lane == 63 || ndn != nid);
            if (lastseg) {
                #pragma unroll
                for (int t = 0; t < 7; ++t) {
                    HU u; u.h = h2p[t];
                    atomicAdd(&aggs[nid * 15 + 2*t],     (float)u.f[0]);
                    atomicAdd(&aggs[nid * 15 + 2*t + 1], (float)u.f[1]);
                }
            }
        }
        __syncthreads();
    }

    // finalize node tid (scalar-pipe f32 weights)
    if (tid < nN) {
        int deg = degs[tid];
        float aggm[HD];
        if (deg > 0) {
            float inv = 1.0f / (float)deg;
            float am[HD];
            #pragma unroll
            for (int k = 0; k < HD; ++k) am[k] = aggs[tid * 15 + k] * inv;
            #pragma unroll
            for (int j = 0; j < HD; ++j) {
                float v = bn12[j];
                #pragma unroll
                for (int k = 0; k < HD; ++k) v = fmaf(am[k], Wn12[k*HD+j], v);
                aggm[j] = v;
            }
        } else {
            #pragma unroll
            for (int j = 0; j < HD; ++j) aggm[j] = 0.f;
        }

        float4 v4 = xn[tid];
        float ipbb = -v4.x*v4.x + v4.y*v4.y + v4.z*v4.z + v4.w*v4.w;
        float h[HD];
        #pragma unroll
        for (int j = 0; j < HD; ++j) {
            float v = fmaf(ipbb, Wn21[j], bn21[j]);
            #pragma unroll
            for (int k = 0; k < HD; ++k) v = fmaf(aggm[k], Wn21[(1+k)*HD+j], v);
            h[j] = fmaxf(v, 0.f);
        }
        float xo[16];
        #pragma unroll
        for (int j = 0; j < HD; ++j) {
            float v = bn22[j];
            #pragma unroll
            for (int k = 0; k < HD; ++k) v = fmaf(h[k], Wn22[k*HD+j], v);
            xo[j] = v;
        }
        float4* op = (float4*)(x_out + (size_t)(nb0 + tid) * 16);
        op[0] = make_float4(xo[0], xo[1], xo[2], xo[3]);
        op[1] = make_float4(xo[4], xo[5], xo[6], xo[7]);
        op[2] = make_float4(xo[8], xo[9], xo[10], xo[11]);
        op[3] = make_float4(xo[12], xo[13], 0.f, 0.f);
    }
}

// ---- pass 4: per-graph mean + global MLP ----
__global__ void __launch_bounds__(256)
graph_kernel(const float* __restrict__ x_out, const int* __restrict__ batch,
             const float* __restrict__ Wg1, const float* __restrict__ bg1,
             const float* __restrict__ Wg2, const float* __restrict__ bg2,
             float* __restrict__ out, int N, int G)
{
    __shared__ float red[256 * 15];
    int g = blockIdx.x;
    int tid = threadIdx.x;

    int lo = lower_bound_i(batch, N, g);
    int hi = lower_bound_i(batch, N, g + 1);

    float acc[HD];
    #pragma unroll
    for (int j = 0; j < HD; ++j) acc[j] = 0.f;

    for (int n = lo + tid; n < hi; n += 256) {
        const float* xp = x_out + (size_t)n * 16;
        #pragma unroll
        for (int j = 0; j < HD; ++j) acc[j] += xp[j];
    }
    #pragma unroll
    for (int j = 0; j < HD; ++j) red[tid * 15 + j] = acc[j];
    __syncthreads();

    for (int s = 128; s >= 1; s >>= 1) {
        if (tid < s) {
            #pragma unroll
            for (int j = 0; j < HD; ++j) red[tid * 15 + j] += red[(tid + s) * 15 + j];
        }
        __syncthreads();
    }

    if (tid == 0) {
        float invc = 1.0f / fmaxf((float)(hi - lo), 1.0f);
        float gm[HD];
        #pragma unroll
        for (int j = 0; j < HD; ++j) gm[j] = red[j] * invc;
        float h[HD];
        #pragma unroll
        for (int j = 0; j < HD; ++j) {
            float v = bg1[j];
            #pragma unroll
            for (int k = 0; k < HD; ++k) v = fmaf(gm[k], Wg1[k*HD+j], v);
            h[j] = fmaxf(v, 0.f);
        }
        #pragma unroll
        for (int o = 0; o < NOUT; ++o) {
            float v = bg2[o];
            #pragma unroll
            for (int k = 0; k < HD; ++k) v = fmaf(h[k], Wg2[k*NOUT+o], v);
            out[g * NOUT + o] = v;
        }
    }
}

extern "C" void kernel_launch(void* const* d_in, const int* in_sizes, int n_in,
                              void* d_out, int out_size, void* d_ws, size_t ws_size,
                              hipStream_t stream) {
    const int N = NN, E = EE, G = GG;

    const float4* x     = (const float4*)d_in[0];
    const int*    eidx  = (const int*)d_in[1];
    const int*    batch = (const int*)d_in[2];
    const float*  We1  = (const float*)d_in[3];
    const float*  be1  = (const float*)d_in[4];
    const float*  We2  = (const float*)d_in[5];
    const float*  be2  = (const float*)d_in[6];
    const float*  Wn11 = (const float*)d_in[7];
    const float*  bn11 = (const float*)d_in[8];
    const float*  Wn12 = (const float*)d_in[9];
    const float*  bn12 = (const float*)d_in[10];
    const float*  Wn21 = (const float*)d_in[11];
    const float*  bn21 = (const float*)d_in[12];
    const float*  Wn22 = (const float*)d_in[13];
    const float*  bn22 = (const float*)d_in[14];
    const float*  Wg1  = (const float*)d_in[15];
    const float*  bg1  = (const float*)d_in[16];
    const float*  Wg2  = (const float*)d_in[17];
    const float*  bg2  = (const float*)d_in[18];

    const int* row = eidx;       // edge_index[0]
    const int* col = eidx + E;   // edge_index[1]

    // workspace layout (bytes) — every buffer fully written before read, no memsets:
    //   ghist  @ 0          NCELL ints  (1,600,512)
    //   excl   @ 2,097,152  NCELL ints  (1,600,512)
    //   btot   @ 3,801,088  NBSCAN ints (784)
    //   bfold  @ 3,802,112  (56)
    //   We1pk  @ 3,802,368  (112)
    //   Cpk    @ 3,802,624  (392)
    //   srcdst @ 4,194,304  E ints      (12,800,000) -> ends 16,994,304
    //   x_out  @ 16,994,304 N*16 floats (12,800,000) -> ends 29,794,304
    char*     ws     = (char*)d_ws;
    int*      ghist  = (int*)(ws + 0);
    int*      excl   = (int*)(ws + 2097152);
    int*      btot   = (int*)(ws + 3801088);
    float*    bfold  = (float*)(ws + 3802112);
    unsigned* We1pk  = (unsigned*)(ws + 3802368);
    unsigned* Cpk    = (unsigned*)(ws + 3802624);
    int*      srcdst = (int*)(ws + 4194304);
    float*    x_out  = (float*)(ws + 16994304);

    dim3 blk(256);
    fold_kernel<<<dim3(1), blk, 0, stream>>>(We1, We2, be2, Wn11, bn11,
                                             bfold, We1pk, Cpk);

    histA<<<dim3(NBLKA), blk, 0, stream>>>(col, ghist);
    scan1_kernel<<<dim3(NBSCAN), dim3(SBS), 0, stream>>>(ghist, excl, btot, NCELL);
    scan2_kernel<<<dim3(1), blk, 0, stream>>>(btot, NBSCAN);
    scatterA<<<dim3(NBLKA), blk, 0, stream>>>(row, col, excl, btot, srcdst);

    bucket_kernel<<<dim3(NBIN), blk, 0, stream>>>(
        x, srcdst, excl, btot,
        We1pk, be1, Wn11, Cpk, bfold,
        Wn12, bn12, Wn21, bn21, Wn22, bn22,
        x_out, N, E);

    graph_kernel<<<dim3(G), blk, 0, stream>>>(x_out, batch, Wg1, bg1, Wg2, bg2,
                                              (float*)d_out, N, G);
}

// Round 11
// 169.157 us; speedup vs baseline: 8.2236x; 1.0504x over previous
//
#include <hip/hip_runtime.h>

#define HD 14
#define NOUT 2
#define NN 200000
#define EE 3200000
#define GG 2000

// bucket config
#define WNODE 128                         // nodes per bucket (c >> 7)
#define NBIN 1563                         // ceil(200000/128)
#define NBLKA 256                         // partition blocks
#define EPERA 12500                       // edges per partition block
#define NCELL (NBIN*NBLKA)                // 400128
#define TILE 2048                         // edges per in-block sort tile

// scan config
#define SBS 256
#define SEL 8
#define CHUNK (SBS*SEL)                   // 2048
#define NBSCAN ((NCELL + CHUNK - 1) / CHUNK)  // 196

typedef __fp16 hv2 __attribute__((ext_vector_type(2)));
union HU { hv2 h; __fp16 f[2]; unsigned u; int i; };
__device__ __forceinline__ hv2 as_h2(unsigned u) { HU x; x.u = u; return x.h; }

__device__ __forceinline__ float psi_f(float v) {
    float r = __logf(1.0f + fabsf(v));
    return __builtin_copysignf(r, v);
}

__device__ __forceinline__ int lower_bound_i(const int* a, int n, int key) {
    int lo = 0, hi = n;
    while (lo < hi) { int mid = (lo + hi) >> 1; if (a[mid] < key) lo = mid + 1; else hi = mid; }
    return lo;
}

// ---- pass 0: fold We2 into Wn11; emit f16-packed weight pairs ----
__global__ void __launch_bounds__(256)
fold_kernel(const float* __restrict__ We1,
            const float* __restrict__ We2, const float* __restrict__ be2,
            const float* __restrict__ Wn11, const float* __restrict__ bn11,
            float* __restrict__ bp, unsigned* __restrict__ We1pk,
            unsigned* __restrict__ Cpk)
{
    __shared__ float sC[HD*HD];
    int t = threadIdx.x;
    if (t < HD*HD) {
        int k = t / HD, j = t % HD;
        float s = 0.f;
        #pragma unroll
        for (int u = 0; u < HD; ++u) s = fmaf(We2[k*HD+u], Wn11[(1+u)*HD+j], s);
        sC[t] = s;
    } else if (t < HD*HD + HD) {
        int j = t - HD*HD;
        float s = bn11[j];
        #pragma unroll
        for (int u = 0; u < HD; ++u) s = fmaf(be2[u], Wn11[(1+u)*HD+j], s);
        bp[j] = s;
    }
    __syncthreads();
    if (t < 7*HD) {                      // Cpk[tt*14+j] = pack(C[2tt][j], C[2tt+1][j])
        int tt = t / HD, j = t % HD;
        HU x; x.h = __builtin_amdgcn_cvt_pkrtz(sC[(2*tt)*HD + j], sC[(2*tt+1)*HD + j]);
        Cpk[t] = x.u;
    } else if (t < 7*HD + 2*HD) {        // We1pk[tt*14+j] = pack(We1[2tt][j], We1[2tt+1][j])
        int q = t - 7*HD;
        int tt = q / HD, j = q % HD;
        HU x; x.h = __builtin_amdgcn_cvt_pkrtz(We1[(2*tt)*HD + j], We1[(2*tt+1)*HD + j]);
        We1pk[q] = x.u;
    }
}

// ---- pass 1: per-(bucket, block) histogram of col>>7, bin-major output ----
__global__ void __launch_bounds__(1024)
histA(const int* __restrict__ col, int* __restrict__ ghist)
{
    __shared__ int hist[NBIN];
    int tid = threadIdx.x;
    for (int i = tid; i < NBIN; i += 1024) hist[i] = 0;
    __syncthreads();
    int j = blockIdx.x;
    int base = j * EPERA;
    for (int it = 0; it < EPERA; it += 1024) {
        int o = it + tid;
        if (o < EPERA) atomicAdd(&hist[col[base + o] >> 7], 1);
    }
    __syncthreads();
    for (int i = tid; i < NBIN; i += 1024) ghist[i * NBLKA + j] = hist[i];
}

// ---- scan of ghist[NCELL] -> excl (chunk-local) + btot (chunk bases) ----
__global__ void __launch_bounds__(SBS)
scan1_kernel(const int* __restrict__ cnt, int* __restrict__ excl,
             int* __restrict__ btot, int n)
{
    __shared__ int lds[SBS];
    int tid = threadIdx.x;
    int base = blockIdx.x * CHUNK + tid * SEL;
    int v[SEL]; int s = 0;
    #pragma unroll
    for (int k = 0; k < SEL; ++k) { int i = base + k; v[k] = (i < n) ? cnt[i] : 0; s += v[k]; }
    lds[tid] = s; __syncthreads();
    for (int off = 1; off < SBS; off <<= 1) {
        int t = (tid >= off) ? lds[tid - off] : 0;
        __syncthreads();
        lds[tid] += t;
        __syncthreads();
    }
    int incl = lds[tid];
    int run = incl - s;
    if (tid == SBS - 1) btot[blockIdx.x] = incl;
    #pragma unroll
    for (int k = 0; k < SEL; ++k) { int i = base + k; if (i < n) excl[i] = run; run += v[k]; }
}

__global__ void __launch_bounds__(256)
scan2_kernel(int* __restrict__ btot, int nb)
{
    __shared__ int lds[256];
    int tid = threadIdx.x;
    int v = (tid < nb) ? btot[tid] : 0;
    lds[tid] = v; __syncthreads();
    for (int off = 1; off < 256; off <<= 1) {
        int t = (tid >= off) ? lds[tid - off] : 0;
        __syncthreads();
        lds[tid] += t;
        __syncthreads();
    }
    if (tid < nb) btot[tid] = lds[tid] - v;   // exclusive chunk bases, in place
}

// ---- pass 2: partition edges into buckets, packed (src | dl<<18) ----
__global__ void __launch_bounds__(1024)
scatterA(const int* __restrict__ row, const int* __restrict__ col,
         const int* __restrict__ excl, const int* __restrict__ btot,
         int* __restrict__ srcdst)
{
    __shared__ int lcount[NBIN];
    int tid = threadIdx.x;
    for (int i = tid; i < NBIN; i += 1024) lcount[i] = 0;
    __syncthreads();
    int j = blockIdx.x;
    int base = j * EPERA;
    for (int it = 0; it < EPERA; it += 1024) {
        int o = it + tid;
        if (o < EPERA) {
            int e = base + o;
            int c = col[e];
            int r = row[e];
            int bb = c >> 7;
            int dl = c & 127;
            int rk = atomicAdd(&lcount[bb], 1);
            int cell = bb * NBLKA + j;
            int pos = excl[cell] + btot[cell >> 11] + rk;
            srcdst[pos] = r | (dl << 18);
        }
    }
}

// ---- pass 3: per-bucket tile counting-sort + edge-parallel fdot2 compute +
//              f16-packed wave-segmented reduction ----
__global__ void __launch_bounds__(256)
bucket_kernel(const float4* __restrict__ x,
              const int* __restrict__ srcdst,
              const int* __restrict__ excl, const int* __restrict__ btot,
              const unsigned* __restrict__ We1pk, const float* __restrict__ be1,
              const float* __restrict__ Wn11,    // row 0 used
              const unsigned* __restrict__ Cpk, const float* __restrict__ bp,
              const float* __restrict__ Wn12, const float* __restrict__ bn12,
              const float* __restrict__ Wn21, const float* __restrict__ bn21,
              const float* __restrict__ Wn22, const float* __restrict__ bn22,
              float* __restrict__ x_out, int N, int E)
{
    __shared__ float4 xn[WNODE];
    __shared__ float nf2[WNODE];
    __shared__ float aggs[WNODE * 15];
    __shared__ int hist[WNODE];
    __shared__ int cursor[WNODE];
    __shared__ int degs[WNODE];
    __shared__ int sorted[TILE];

    int tid = threadIdx.x;
    int lane = tid & 63;
    int wv = tid >> 6;

    int b = blockIdx.x;
    int nb0 = b * WNODE;
    int nN = min(WNODE, N - nb0);

    if (tid < WNODE) degs[tid] = 0;
    for (int i = tid; i < WNODE * 15; i += 256) aggs[i] = 0.f;

    if (tid < nN) {
        float4 v = x[nb0 + tid];
        xn[tid] = v;
        nf2[tid] = psi_f(-v.x*v.x + v.y*v.y + v.z*v.z + v.w*v.w);
    }

    int c0 = b * NBLKA;
    int lo = excl[c0] + btot[c0 >> 11];
    int hi;
    if (b + 1 < NBIN) { int c1 = (b + 1) * NBLKA; hi = excl[c1] + btot[c1 >> 11]; }
    else hi = E;

    __syncthreads();

    for (int tb = lo; tb < hi; tb += TILE) {
        int tsz = min(TILE, hi - tb);

        if (tid < WNODE) hist[tid] = 0;
        __syncthreads();

        // count
        for (int o = tid; o < tsz; o += 256) {
            int p = srcdst[tb + o];
            atomicAdd(&hist[p >> 18], 1);
        }
        __syncthreads();

        // inclusive scan over WNODE bins (first WNODE threads)
        if (tid < WNODE) cursor[tid] = hist[tid];
        __syncthreads();
        for (int st = 1; st < WNODE; st <<= 1) {
            int v = (tid >= st && tid < WNODE) ? cursor[tid - st] : 0;
            __syncthreads();
            if (tid < WNODE) cursor[tid] += v;
            __syncthreads();
        }
        if (tid < WNODE) {
            int exb = cursor[tid] - hist[tid];
            degs[tid] += hist[tid];
            cursor[tid] = exb;
        }
        __syncthreads();

        // scatter into sorted[]
        for (int o = tid; o < tsz; o += 256) {
            int p = srcdst[tb + o];
            int pos = atomicAdd(&cursor[p >> 18], 1);
            sorted[pos] = p;
        }
        __syncthreads();

        // edge-parallel compute + packed-f16 wave-segmented reduction
        for (int cb = wv * 64; cb < tsz; cb += 256) {
            int o = cb + lane;
            bool valid = (o < tsz);
            int p = valid ? sorted[o] : 0;
            int nid = valid ? (p >> 18) : WNODE;          // sentinel for tail lanes

            hv2 h2p[7];
            HU uz; uz.u = 0;
            #pragma unroll
            for (int t = 0; t < 7; ++t) h2p[t] = uz.h;

            if (valid) {
                float4 a = x[p & 262143];
                float4 bx = xn[nid];
                float f2 = nf2[nid];

                float f0 = -a.x*a.x + a.y*a.y + a.z*a.z + a.w*a.w;
                float f1 = -a.x*bx.x + a.y*bx.y + a.z*bx.z + a.w*bx.w;
                float dx = a.x-bx.x, dy = a.y-bx.y, dz = a.z-bx.z, dw = a.w-bx.w;
                float f3 = psi_f(-dx*dx + dy*dy + dz*dz + dw*dw);

                hv2 f01 = __builtin_amdgcn_cvt_pkrtz(f0, f1);
                hv2 f23 = __builtin_amdgcn_cvt_pkrtz(f2, f3);

                float h1[HD];
                #pragma unroll
                for (int j = 0; j < HD; ++j) {
                    float v = __builtin_amdgcn_fdot2(f23, as_h2(We1pk[HD + j]), be1[j], false);
                    v = __builtin_amdgcn_fdot2(f01, as_h2(We1pk[j]), v, false);
                    h1[j] = fmaxf(v, 0.f);
                }
                hv2 h1p[7];
                #pragma unroll
                for (int t = 0; t < 7; ++t) h1p[t] = __builtin_amdgcn_cvt_pkrtz(h1[2*t], h1[2*t+1]);

                float h2[HD];
                #pragma unroll
                for (int j = 0; j < HD; ++j) {
                    float v = fmaf(f0, Wn11[j], bp[j]);
                    #pragma unroll
                    for (int t = 0; t < 7; ++t) v = __builtin_amdgcn_fdot2(h1p[t], as_h2(Cpk[t*HD + j]), v, false);
                    h2[j] = fmaxf(v, 0.f);
                }
                #pragma unroll
                for (int t = 0; t < 7; ++t) h2p[t] = __builtin_amdgcn_cvt_pkrtz(h2[2*t], h2[2*t+1]);
            }

            // segmented inclusive sum over non-decreasing nid (packed f16 pairs)
            #pragma unroll
            for (int st = 1; st < 64; st <<= 1) {
                int nup = __shfl_up(nid, st, 64);
                bool take = (lane >= st) && (nup == nid);
                #pragma unroll
                for (int t = 0; t < 7; ++t) {
                    HU u; u.h = h2p[t];
                    u.i = __shfl_up(u.i, st, 64);
                    if (take) h2p[t] += u.h;
                }
            }
            int ndn = __shfl_down(nid, 1, 64);
            bool lastseg = valid && (lane == 63 || ndn != nid);
            if (lastseg) {
                #pragma unroll
                for (int t = 0; t < 7; ++t) {
                    HU u; u.h = h2p[t];
                    atomicAdd(&aggs[nid * 15 + 2*t],     (float)u.f[0]);
                    atomicAdd(&aggs[nid * 15 + 2*t + 1], (float)u.f[1]);
                }
            }
        }
        __syncthreads();
    }

    // finalize node tid (scalar-pipe f32 weights)
    if (tid < nN) {
        int deg = degs[tid];
        float aggm[HD];
        if (deg > 0) {
            float inv = 1.0f / (float)deg;
            float am[HD];
            #pragma unroll
            for (int k = 0; k < HD; ++k) am[k] = aggs[tid * 15 + k] * inv;
            #pragma unroll
            for (int j = 0; j < HD; ++j) {
                float v = bn12[j];
                #pragma unroll
                for (int k = 0; k < HD; ++k) v = fmaf(am[k], Wn12[k*HD+j], v);
                aggm[j] = v;
            }
        } else {
            #pragma unroll
            for (int j = 0; j < HD; ++j) aggm[j] = 0.f;
        }

        float4 v4 = xn[tid];
        float ipbb = -v4.x*v4.x + v4.y*v4.y + v4.z*v4.z + v4.w*v4.w;
        float h[HD];
        #pragma unroll
        for (int j = 0; j < HD; ++j) {
            float v = fmaf(ipbb, Wn21[j], bn21[j]);
            #pragma unroll
            for (int k = 0; k < HD; ++k) v = fmaf(aggm[k], Wn21[(1+k)*HD+j], v);
            h[j] = fmaxf(v, 0.f);
        }
        float xo[16];
        #pragma unroll
        for (int j = 0; j < HD; ++j) {
            float v = bn22[j];
            #pragma unroll
            for (int k = 0; k < HD; ++k) v = fmaf(h[k], Wn22[k*HD+j], v);
            xo[j] = v;
        }
        float4* op = (float4*)(x_out + (size_t)(nb0 + tid) * 16);
        op[0] = make_float4(xo[0], xo[1], xo[2], xo[3]);
        op[1] = make_float4(xo[4], xo[5], xo[6], xo[7]);
        op[2] = make_float4(xo[8], xo[9], xo[10], xo[11]);
        op[3] = make_float4(xo[12], xo[13], 0.f, 0.f);
    }
}

// ---- pass 4: per-graph mean + global MLP ----
__global__ void __launch_bounds__(256)
graph_kernel(const float* __restrict__ x_out, const int* __restrict__ batch,
             const float* __restrict__ Wg1, const float* __restrict__ bg1,
             const float* __restrict__ Wg2, const float* __restrict__ bg2,
             float* __restrict__ out, int N, int G)
{
    __shared__ float red[256 * 15];
    int g = blockIdx.x;
    int tid = threadIdx.x;

    int lo = lower_bound_i(batch, N, g);
    int hi = lower_bound_i(batch, N, g + 1);

    float acc[HD];
    #pragma unroll
    for (int j = 0; j < HD; ++j) acc[j] = 0.f;

    for (int n = lo + tid; n < hi; n += 256) {
        const float* xp = x_out + (size_t)n * 16;
        #pragma unroll
        for (int j = 0; j < HD; ++j) acc[j] += xp[j];
    }
    #pragma unroll
    for (int j = 0; j < HD; ++j) red[tid * 15 + j] = acc[j];
    __syncthreads();

    for (int s = 128; s >= 1; s >>= 1) {
        if (tid < s) {
            #pragma unroll
            for (int j = 0; j < HD; ++j) red[tid * 15 + j] += red[(tid + s) * 15 + j];
        }
        __syncthreads();
    }

    if (tid == 0) {
        float invc = 1.0f / fmaxf((float)(hi - lo), 1.0f);
        float gm[HD];
        #pragma unroll
        for (int j = 0; j < HD; ++j) gm[j] = red[j] * invc;
        float h[HD];
        #pragma unroll
        for (int j = 0; j < HD; ++j) {
            float v = bg1[j];
            #pragma unroll
            for (int k = 0; k < HD; ++k) v = fmaf(gm[k], Wg1[k*HD+j], v);
            h[j] = fmaxf(v, 0.f);
        }
        #pragma unroll
        for (int o = 0; o < NOUT; ++o) {
            float v = bg2[o];
            #pragma unroll
            for (int k = 0; k < HD; ++k) v = fmaf(h[k], Wg2[k*NOUT+o], v);
            out[g * NOUT + o] = v;
        }
    }
}

extern "C" void kernel_launch(void* const* d_in, const int* in_sizes, int n_in,
                              void* d_out, int out_size, void* d_ws, size_t ws_size,
                              hipStream_t stream) {
    const int N = NN, E = EE, G = GG;

    const float4* x     = (const float4*)d_in[0];
    const int*    eidx  = (const int*)d_in[1];
    const int*    batch = (const int*)d_in[2];
    const float*  We1  = (const float*)d_in[3];
    const float*  be1  = (const float*)d_in[4];
    const float*  We2  = (const float*)d_in[5];
    const float*  be2  = (const float*)d_in[6];
    const float*  Wn11 = (const float*)d_in[7];
    const float*  bn11 = (const float*)d_in[8];
    const float*  Wn12 = (const float*)d_in[9];
    const float*  bn12 = (const float*)d_in[10];
    const float*  Wn21 = (const float*)d_in[11];
    const float*  bn21 = (const float*)d_in[12];
    const float*  Wn22 = (const float*)d_in[13];
    const float*  bn22 = (const float*)d_in[14];
    const float*  Wg1  = (const float*)d_in[15];
    const float*  bg1  = (const float*)d_in[16];
    const float*  Wg2  = (const float*)d_in[17];
    const float*  bg2  = (const float*)d_in[18];

    const int* row = eidx;       // edge_index[0]
    const int* col = eidx + E;   // edge_index[1]

    // workspace layout (bytes) — every buffer fully written before read, no memsets:
    //   ghist  @ 0          NCELL ints  (1,600,512)
    //   excl   @ 2,097,152  NCELL ints  (1,600,512)
    //   btot   @ 3,801,088  NBSCAN ints (784)
    //   bfold  @ 3,802,112  (56)
    //   We1pk  @ 3,802,368  (112)
    //   Cpk    @ 3,802,624  (392)
    //   srcdst @ 4,194,304  E ints      (12,800,000) -> ends 16,994,304
    //   x_out  @ 16,994,304 N*16 floats (12,800,000) -> ends 29,794,304
    char*     ws     = (char*)d_ws;
    int*      ghist  = (int*)(ws + 0);
    int*      excl   = (int*)(ws + 2097152);
    int*      btot   = (int*)(ws + 3801088);
    float*    bfold  = (float*)(ws + 3802112);
    unsigned* We1pk  = (unsigned*)(ws + 3802368);
    unsigned* Cpk    = (unsigned*)(ws + 3802624);
    int*      srcdst = (int*)(ws + 4194304);
    float*    x_out  = (float*)(ws + 16994304);

    dim3 blk(256);
    fold_kernel<<<dim3(1), blk, 0, stream>>>(We1, We2, be2, Wn11, bn11,
                                             bfold, We1pk, Cpk);

    histA<<<dim3(NBLKA), dim3(1024), 0, stream>>>(col, ghist);
    scan1_kernel<<<dim3(NBSCAN), dim3(SBS), 0, stream>>>(ghist, excl, btot, NCELL);
    scan2_kernel<<<dim3(1), blk, 0, stream>>>(btot, NBSCAN);
    scatterA<<<dim3(NBLKA), dim3(1024), 0, stream>>>(row, col, excl, btot, srcdst);

    bucket_kernel<<<dim3(NBIN), blk, 0, stream>>>(
        x, srcdst, excl, btot,
        We1pk, be1, Wn11, Cpk, bfold,
        Wn12, bn12, Wn21, bn21, Wn22, bn22,
        x_out, N, E);

    graph_kernel<<<dim3(G), blk, 0, stream>>>(x_out, batch, Wg1, bg1, Wg2, bg2,
                                              (float*)d_out, N, G);
}

// Round 12
// 138.136 us; speedup vs baseline: 10.0704x; 1.2246x over previous
//
#include <hip/hip_runtime.h>

#define HD 14
#define NOUT 2
#define NN 200000
#define EE 3200000
#define GG 2000

// bucket config
#define WNODE 128                         // nodes per bucket (c >> 7)
#define NBIN 1563                         // ceil(200000/128)
#define NBLKA 256                         // partition blocks
#define EPERA 12500                       // edges per partition block
#define NCELL (NBIN*NBLKA)                // 400128
#define TILE 2048                         // edges per in-block sort tile

// scan config
#define SBS 256
#define SEL 8
#define CHUNK (SBS*SEL)                   // 2048
#define NBSCAN ((NCELL + CHUNK - 1) / CHUNK)  // 196

typedef __fp16 hv2 __attribute__((ext_vector_type(2)));
union HU { hv2 h; __fp16 f[2]; unsigned u; int i; };
__device__ __forceinline__ hv2 as_h2(unsigned u) { HU x; x.u = u; return x.h; }

__device__ __forceinline__ float psi_f(float v) {
    float r = __logf(1.0f + fabsf(v));
    return __builtin_copysignf(r, v);
}

__device__ __forceinline__ int lower_bound_i(const int* a, int n, int key) {
    int lo = 0, hi = n;
    while (lo < hi) { int mid = (lo + hi) >> 1; if (a[mid] < key) lo = mid + 1; else hi = mid; }
    return lo;
}

// ---- pass 0: fold We2 into Wn11; emit f16-packed weight pairs ----
__global__ void __launch_bounds__(256)
fold_kernel(const float* __restrict__ We1,
            const float* __restrict__ We2, const float* __restrict__ be2,
            const float* __restrict__ Wn11, const float* __restrict__ bn11,
            float* __restrict__ bp, unsigned* __restrict__ We1pk,
            unsigned* __restrict__ Cpk)
{
    __shared__ float sC[HD*HD];
    int t = threadIdx.x;
    if (t < HD*HD) {
        int k = t / HD, j = t % HD;
        float s = 0.f;
        #pragma unroll
        for (int u = 0; u < HD; ++u) s = fmaf(We2[k*HD+u], Wn11[(1+u)*HD+j], s);
        sC[t] = s;
    } else if (t < HD*HD + HD) {
        int j = t - HD*HD;
        float s = bn11[j];
        #pragma unroll
        for (int u = 0; u < HD; ++u) s = fmaf(be2[u], Wn11[(1+u)*HD+j], s);
        bp[j] = s;
    }
    __syncthreads();
    if (t < 7*HD) {                      // Cpk[tt*14+j] = pack(C[2tt][j], C[2tt+1][j])
        int tt = t / HD, j = t % HD;
        HU x; x.h = __builtin_amdgcn_cvt_pkrtz(sC[(2*tt)*HD + j], sC[(2*tt+1)*HD + j]);
        Cpk[t] = x.u;
    } else if (t < 7*HD + 2*HD) {        // We1pk[tt*14+j] = pack(We1[2tt][j], We1[2tt+1][j])
        int q = t - 7*HD;
        int tt = q / HD, j = q % HD;
        HU x; x.h = __builtin_amdgcn_cvt_pkrtz(We1[(2*tt)*HD + j], We1[(2*tt+1)*HD + j]);
        We1pk[q] = x.u;
    }
}

// ---- pass 1: per-(bucket, block) histogram of col>>7, bin-major output ----
__global__ void __launch_bounds__(1024)
histA(const int* __restrict__ col, int* __restrict__ ghist)
{
    __shared__ int hist[NBIN];
    int tid = threadIdx.x;
    for (int i = tid; i < NBIN; i += 1024) hist[i] = 0;
    __syncthreads();
    int j = blockIdx.x;
    int base = j * EPERA;
    for (int it = 0; it < EPERA; it += 1024) {
        int o = it + tid;
        if (o < EPERA) atomicAdd(&hist[col[base + o] >> 7], 1);
    }
    __syncthreads();
    for (int i = tid; i < NBIN; i += 1024) ghist[i * NBLKA + j] = hist[i];
}

// ---- scan of ghist[NCELL] -> excl (chunk-local) + btot (chunk bases) ----
__global__ void __launch_bounds__(SBS)
scan1_kernel(const int* __restrict__ cnt, int* __restrict__ excl,
             int* __restrict__ btot, int n)
{
    __shared__ int lds[SBS];
    int tid = threadIdx.x;
    int base = blockIdx.x * CHUNK + tid * SEL;
    int v[SEL]; int s = 0;
    #pragma unroll
    for (int k = 0; k < SEL; ++k) { int i = base + k; v[k] = (i < n) ? cnt[i] : 0; s += v[k]; }
    lds[tid] = s; __syncthreads();
    for (int off = 1; off < SBS; off <<= 1) {
        int t = (tid >= off) ? lds[tid - off] : 0;
        __syncthreads();
        lds[tid] += t;
        __syncthreads();
    }
    int incl = lds[tid];
    int run = incl - s;
    if (tid == SBS - 1) btot[blockIdx.x] = incl;
    #pragma unroll
    for (int k = 0; k < SEL; ++k) { int i = base + k; if (i < n) excl[i] = run; run += v[k]; }
}

__global__ void __launch_bounds__(256)
scan2_kernel(int* __restrict__ btot, int nb)
{
    __shared__ int lds[256];
    int tid = threadIdx.x;
    int v = (tid < nb) ? btot[tid] : 0;
    lds[tid] = v; __syncthreads();
    for (int off = 1; off < 256; off <<= 1) {
        int t = (tid >= off) ? lds[tid - off] : 0;
        __syncthreads();
        lds[tid] += t;
        __syncthreads();
    }
    if (tid < nb) btot[tid] = lds[tid] - v;   // exclusive chunk bases, in place
}

// ---- pass 2: partition via LDS staging; coalesced global writeout ----
// Block j stages its 12500 edges in globally-sorted order in LDS, then writes
// runs out coalesced (consecutive o -> consecutive global pos within a cell).
__global__ void __launch_bounds__(1024)
scatterA(const int* __restrict__ row, const int* __restrict__ col,
         const int* __restrict__ ghist,
         const int* __restrict__ excl, const int* __restrict__ btot,
         int* __restrict__ srcdst)
{
    __shared__ int lofs[NBIN + 1];
    __shared__ int cursor[NBIN + 1];
    __shared__ int delta[NBIN + 1];
    __shared__ int ssum[1024];
    __shared__ int lval[EPERA];
    __shared__ int ldel[EPERA];

    int tid = threadIdx.x;
    int j = blockIdx.x;

    // (a) load this block's count column from ghist; 2 contiguous bins/thread
    int b0 = 2 * tid, b1 = 2 * tid + 1;
    int c0 = (b0 < NBIN) ? ghist[b0 * NBLKA + j] : 0;
    int c1 = (b1 < NBIN) ? ghist[b1 * NBLKA + j] : 0;
    ssum[tid] = c0 + c1;
    __syncthreads();

    // inclusive Hillis-Steele scan over 1024 thread-sums
    for (int off = 1; off < 1024; off <<= 1) {
        int t = (tid >= off) ? ssum[tid - off] : 0;
        __syncthreads();
        ssum[tid] += t;
        __syncthreads();
    }
    int base = ssum[tid] - (c0 + c1);         // exclusive base for this thread
    if (b0 <= NBIN) { lofs[b0] = base; cursor[b0] = base; }
    if (b1 <= NBIN) { lofs[b1] = base + c0; cursor[b1] = base + c0; }
    __syncthreads();

    // (b) delta[bin] = global cell base - local offset
    for (int b = tid; b < NBIN; b += 1024) {
        int cell = b * NBLKA + j;
        delta[b] = excl[cell] + btot[cell >> 11] - lofs[b];
    }
    __syncthreads();

    // (c) single pass: rank into LDS staging
    int ebase = j * EPERA;
    for (int o = tid; o < EPERA; o += 1024) {
        int e = ebase + o;
        int c = col[e];
        int r = row[e];
        int bin = c >> 7;
        int dl = c & 127;
        int pos = atomicAdd(&cursor[bin], 1);
        lval[pos] = r | (dl << 18);
        ldel[pos] = delta[bin];
    }
    __syncthreads();

    // (d) coalesced writeout
    for (int o = tid; o < EPERA; o += 1024) {
        srcdst[o + ldel[o]] = lval[o];
    }
}

// ---- pass 3: per-bucket tile counting-sort + edge-parallel fdot2 compute +
//              f16-packed wave-segmented reduction ----
__global__ void __launch_bounds__(256)
bucket_kernel(const float4* __restrict__ x,
              const int* __restrict__ srcdst,
              const int* __restrict__ excl, const int* __restrict__ btot,
              const unsigned* __restrict__ We1pk, const float* __restrict__ be1,
              const float* __restrict__ Wn11,    // row 0 used
              const unsigned* __restrict__ Cpk, const float* __restrict__ bp,
              const float* __restrict__ Wn12, const float* __restrict__ bn12,
              const float* __restrict__ Wn21, const float* __restrict__ bn21,
              const float* __restrict__ Wn22, const float* __restrict__ bn22,
              float* __restrict__ x_out, int N, int E)
{
    __shared__ float4 xn[WNODE];
    __shared__ float nf2[WNODE];
    __shared__ float aggs[WNODE * 15];
    __shared__ int hist[WNODE];
    __shared__ int cursor[WNODE];
    __shared__ int degs[WNODE];
    __shared__ int sorted[TILE];

    int tid = threadIdx.x;
    int lane = tid & 63;
    int wv = tid >> 6;

    int b = blockIdx.x;
    int nb0 = b * WNODE;
    int nN = min(WNODE, N - nb0);

    if (tid < WNODE) degs[tid] = 0;
    for (int i = tid; i < WNODE * 15; i += 256) aggs[i] = 0.f;

    if (tid < nN) {
        float4 v = x[nb0 + tid];
        xn[tid] = v;
        nf2[tid] = psi_f(-v.x*v.x + v.y*v.y + v.z*v.z + v.w*v.w);
    }

    int c0 = b * NBLKA;
    int lo = excl[c0] + btot[c0 >> 11];
    int hi;
    if (b + 1 < NBIN) { int c1 = (b + 1) * NBLKA; hi = excl[c1] + btot[c1 >> 11]; }
    else hi = E;

    __syncthreads();

    for (int tb = lo; tb < hi; tb += TILE) {
        int tsz = min(TILE, hi - tb);

        if (tid < WNODE) hist[tid] = 0;
        __syncthreads();

        // count
        for (int o = tid; o < tsz; o += 256) {
            int p = srcdst[tb + o];
            atomicAdd(&hist[p >> 18], 1);
        }
        __syncthreads();

        // inclusive scan over WNODE bins (first WNODE threads)
        if (tid < WNODE) cursor[tid] = hist[tid];
        __syncthreads();
        for (int st = 1; st < WNODE; st <<= 1) {
            int v = (tid >= st && tid < WNODE) ? cursor[tid - st] : 0;
            __syncthreads();
            if (tid < WNODE) cursor[tid] += v;
            __syncthreads();
        }
        if (tid < WNODE) {
            int exb = cursor[tid] - hist[tid];
            degs[tid] += hist[tid];
            cursor[tid] = exb;
        }
        __syncthreads();

        // scatter into sorted[]
        for (int o = tid; o < tsz; o += 256) {
            int p = srcdst[tb + o];
            int pos = atomicAdd(&cursor[p >> 18], 1);
            sorted[pos] = p;
        }
        __syncthreads();

        // edge-parallel compute + packed-f16 wave-segmented reduction
        for (int cb = wv * 64; cb < tsz; cb += 256) {
            int o = cb + lane;
            bool valid = (o < tsz);
            int p = valid ? sorted[o] : 0;
            int nid = valid ? (p >> 18) : WNODE;          // sentinel for tail lanes

            hv2 h2p[7];
            HU uz; uz.u = 0;
            #pragma unroll
            for (int t = 0; t < 7; ++t) h2p[t] = uz.h;

            if (valid) {
                float4 a = x[p & 262143];
                float4 bx = xn[nid];
                float f2 = nf2[nid];

                float f0 = -a.x*a.x + a.y*a.y + a.z*a.z + a.w*a.w;
                float f1 = -a.x*bx.x + a.y*bx.y + a.z*bx.z + a.w*bx.w;
                float dx = a.x-bx.x, dy = a.y-bx.y, dz = a.z-bx.z, dw = a.w-bx.w;
                float f3 = psi_f(-dx*dx + dy*dy + dz*dz + dw*dw);

                hv2 f01 = __builtin_amdgcn_cvt_pkrtz(f0, f1);
                hv2 f23 = __builtin_amdgcn_cvt_pkrtz(f2, f3);

                float h1[HD];
                #pragma unroll
                for (int j = 0; j < HD; ++j) {
                    float v = __builtin_amdgcn_fdot2(f23, as_h2(We1pk[HD + j]), be1[j], false);
                    v = __builtin_amdgcn_fdot2(f01, as_h2(We1pk[j]), v, false);
                    h1[j] = fmaxf(v, 0.f);
                }
                hv2 h1p[7];
                #pragma unroll
                for (int t = 0; t < 7; ++t) h1p[t] = __builtin_amdgcn_cvt_pkrtz(h1[2*t], h1[2*t+1]);

                float h2[HD];
                #pragma unroll
                for (int j = 0; j < HD; ++j) {
                    float v = fmaf(f0, Wn11[j], bp[j]);
                    #pragma unroll
                    for (int t = 0; t < 7; ++t) v = __builtin_amdgcn_fdot2(h1p[t], as_h2(Cpk[t*HD + j]), v, false);
                    h2[j] = fmaxf(v, 0.f);
                }
                #pragma unroll
                for (int t = 0; t < 7; ++t) h2p[t] = __builtin_amdgcn_cvt_pkrtz(h2[2*t], h2[2*t+1]);
            }

            // segmented inclusive sum over non-decreasing nid (packed f16 pairs)
            #pragma unroll
            for (int st = 1; st < 64; st <<= 1) {
                int nup = __shfl_up(nid, st, 64);
                bool take = (lane >= st) && (nup == nid);
                #pragma unroll
                for (int t = 0; t < 7; ++t) {
                    HU u; u.h = h2p[t];
                    u.i = __shfl_up(u.i, st, 64);
                    if (take) h2p[t] += u.h;
                }
            }
            int ndn = __shfl_down(nid, 1, 64);
            bool lastseg = valid && (lane == 63 || ndn != nid);
            if (lastseg) {
                #pragma unroll
                for (int t = 0; t < 7; ++t) {
                    HU u; u.h = h2p[t];
                    atomicAdd(&aggs[nid * 15 + 2*t],     (float)u.f[0]);
                    atomicAdd(&aggs[nid * 15 + 2*t + 1], (float)u.f[1]);
                }
            }
        }
        __syncthreads();
    }

    // finalize node tid (scalar-pipe f32 weights)
    if (tid < nN) {
        int deg = degs[tid];
        float aggm[HD];
        if (deg > 0) {
            float inv = 1.0f / (float)deg;
            float am[HD];
            #pragma unroll
            for (int k = 0; k < HD; ++k) am[k] = aggs[tid * 15 + k] * inv;
            #pragma unroll
            for (int j = 0; j < HD; ++j) {
                float v = bn12[j];
                #pragma unroll
                for (int k = 0; k < HD; ++k) v = fmaf(am[k], Wn12[k*HD+j], v);
                aggm[j] = v;
            }
        } else {
            #pragma unroll
            for (int j = 0; j < HD; ++j) aggm[j] = 0.f;
        }

        float4 v4 = xn[tid];
        float ipbb = -v4.x*v4.x + v4.y*v4.y + v4.z*v4.z + v4.w*v4.w;
        float h[HD];
        #pragma unroll
        for (int j = 0; j < HD; ++j) {
            float v = fmaf(ipbb, Wn21[j], bn21[j]);
            #pragma unroll
            for (int k = 0; k < HD; ++k) v = fmaf(aggm[k], Wn21[(1+k)*HD+j], v);
            h[j] = fmaxf(v, 0.f);
        }
        float xo[16];
        #pragma unroll
        for (int j = 0; j < HD; ++j) {
            float v = bn22[j];
            #pragma unroll
            for (int k = 0; k < HD; ++k) v = fmaf(h[k], Wn22[k*HD+j], v);
            xo[j] = v;
        }
        float4* op = (float4*)(x_out + (size_t)(nb0 + tid) * 16);
        op[0] = make_float4(xo[0], xo[1], xo[2], xo[3]);
        op[1] = make_float4(xo[4], xo[5], xo[6], xo[7]);
        op[2] = make_float4(xo[8], xo[9], xo[10], xo[11]);
        op[3] = make_float4(xo[12], xo[13], 0.f, 0.f);
    }
}

// ---- pass 4: per-graph mean + global MLP ----
__global__ void __launch_bounds__(256)
graph_kernel(const float* __restrict__ x_out, const int* __restrict__ batch,
             const float* __restrict__ Wg1, const float* __restrict__ bg1,
             const float* __restrict__ Wg2, const float* __restrict__ bg2,
             float* __restrict__ out, int N, int G)
{
    __shared__ float red[256 * 15];
    int g = blockIdx.x;
    int tid = threadIdx.x;

    int lo = lower_bound_i(batch, N, g);
    int hi = lower_bound_i(batch, N, g + 1);

    float acc[HD];
    #pragma unroll
    for (int j = 0; j < HD; ++j) acc[j] = 0.f;

    for (int n = lo + tid; n < hi; n += 256) {
        const float* xp = x_out + (size_t)n * 16;
        #pragma unroll
        for (int j = 0; j < HD; ++j) acc[j] += xp[j];
    }
    #pragma unroll
    for (int j = 0; j < HD; ++j) red[tid * 15 + j] = acc[j];
    __syncthreads();

    for (int s = 128; s >= 1; s >>= 1) {
        if (tid < s) {
            #pragma unroll
            for (int j = 0; j < HD; ++j) red[tid * 15 + j] += red[(tid + s) * 15 + j];
        }
        __syncthreads();
    }

    if (tid == 0) {
        float invc = 1.0f / fmaxf((float)(hi - lo), 1.0f);
        float gm[HD];
        #pragma unroll
        for (int j = 0; j < HD; ++j) gm[j] = red[j] * invc;
        float h[HD];
        #pragma unroll
        for (int j = 0; j < HD; ++j) {
            float v = bg1[j];
            #pragma unroll
            for (int k = 0; k < HD; ++k) v = fmaf(gm[k], Wg1[k*HD+j], v);
            h[j] = fmaxf(v, 0.f);
        }
        #pragma unroll
        for (int o = 0; o < NOUT; ++o) {
            float v = bg2[o];
            #pragma unroll
            for (int k = 0; k < HD; ++k) v = fmaf(h[k], Wg2[k*NOUT+o], v);
            out[g * NOUT + o] = v;
        }
    }
}

extern "C" void kernel_launch(void* const* d_in, const int* in_sizes, int n_in,
                              void* d_out, int out_size, void* d_ws, size_t ws_size,
                              hipStream_t stream) {
    const int N = NN, E = EE, G = GG;

    const float4* x     = (const float4*)d_in[0];
    const int*    eidx  = (const int*)d_in[1];
    const int*    batch = (const int*)d_in[2];
    const float*  We1  = (const float*)d_in[3];
    const float*  be1  = (const float*)d_in[4];
    const float*  We2  = (const float*)d_in[5];
    const float*  be2  = (const float*)d_in[6];
    const float*  Wn11 = (const float*)d_in[7];
    const float*  bn11 = (const float*)d_in[8];
    const float*  Wn12 = (const float*)d_in[9];
    const float*  bn12 = (const float*)d_in[10];
    const float*  Wn21 = (const float*)d_in[11];
    const float*  bn21 = (const float*)d_in[12];
    const float*  Wn22 = (const float*)d_in[13];
    const float*  bn22 = (const float*)d_in[14];
    const float*  Wg1  = (const float*)d_in[15];
    const float*  bg1  = (const float*)d_in[16];
    const float*  Wg2  = (const float*)d_in[17];
    const float*  bg2  = (const float*)d_in[18];

    const int* row = eidx;       // edge_index[0]
    const int* col = eidx + E;   // edge_index[1]

    // workspace layout (bytes) — every buffer fully written before read, no memsets:
    //   ghist  @ 0          NCELL ints  (1,600,512)
    //   excl   @ 2,097,152  NCELL ints  (1,600,512)
    //   btot   @ 3,801,088  NBSCAN ints (784)
    //   bfold  @ 3,802,112  (56)
    //   We1pk  @ 3,802,368  (112)
    //   Cpk    @ 3,802,624  (392)
    //   srcdst @ 4,194,304  E ints      (12,800,000) -> ends 16,994,304
    //   x_out  @ 16,994,304 N*16 floats (12,800,000) -> ends 29,794,304
    char*     ws     = (char*)d_ws;
    int*      ghist  = (int*)(ws + 0);
    int*      excl   = (int*)(ws + 2097152);
    int*      btot   = (int*)(ws + 3801088);
    float*    bfold  = (float*)(ws + 3802112);
    unsigned* We1pk  = (unsigned*)(ws + 3802368);
    unsigned* Cpk    = (unsigned*)(ws + 3802624);
    int*      srcdst = (int*)(ws + 4194304);
    float*    x_out  = (float*)(ws + 16994304);

    dim3 blk(256);
    fold_kernel<<<dim3(1), blk, 0, stream>>>(We1, We2, be2, Wn11, bn11,
                                             bfold, We1pk, Cpk);

    histA<<<dim3(NBLKA), dim3(1024), 0, stream>>>(col, ghist);
    scan1_kernel<<<dim3(NBSCAN), dim3(SBS), 0, stream>>>(ghist, excl, btot, NCELL);
    scan2_kernel<<<dim3(1), blk, 0, stream>>>(btot, NBSCAN);
    scatterA<<<dim3(NBLKA), dim3(1024), 0, stream>>>(row, col, ghist, excl, btot, srcdst);

    bucket_kernel<<<dim3(NBIN), blk, 0, stream>>>(
        x, srcdst, excl, btot,
        We1pk, be1, Wn11, Cpk, bfold,
        Wn12, bn12, Wn21, bn21, Wn22, bn22,
        x_out, N, E);

    graph_kernel<<<dim3(G), blk, 0, stream>>>(x_out, batch, Wg1, bg1, Wg2, bg2,
                                              (float*)d_out, N, G);
}